// Round 9
// baseline (344.134 us; speedup 1.0000x reference)
//
#include <hip/hip_runtime.h>
#include <math.h>

#define BATCH 16
#define CDIM 256
#define HW 9216
#define RDIM 32
#define SPLITS 16
#define KSLAB (HW / SPLITS)   /* 576 */
#define KCH 32                /* gram k-columns per chunk */
#define NCH (KSLAB / KCH)     /* 18, even */

#define BN 128                /* out_kernel n-tile */
#define BK 64                 /* out_kernel k-chunk */
#define VOFF 32768            /* v^T tile byte offset inside shared block */
#define NTILES (HW / BN)      /* 72 */

typedef __attribute__((ext_vector_type(8))) short short8;
typedef __attribute__((ext_vector_type(4))) short short4_t;
typedef __attribute__((ext_vector_type(4))) float f32x4;
typedef __attribute__((ext_vector_type(8))) _Float16 half8;

__device__ __forceinline__ unsigned short bf16_rne(float x) {
    union { float f; unsigned u; } a; a.f = x;
    return (unsigned short)((a.u + 0x7fffu + ((a.u >> 16) & 1u)) >> 16);
}
__device__ __forceinline__ unsigned pack2(float lo, float hi) {
    return (unsigned)bf16_rne(lo) | ((unsigned)bf16_rne(hi) << 16);
}

// Non-draining barrier: ds ops visible, global loads STAY IN FLIGHT (gram only).
__device__ __forceinline__ void lds_barrier() {
    asm volatile("s_waitcnt lgkmcnt(0)" ::: "memory");
    __builtin_amdgcn_s_barrier();
}

// gram fp16 tile [256 rows][32 k], row stride 64 B (2-way max conflicts).
__device__ __forceinline__ int gswz16(int row, int k) {
    int byte = (row << 6) + (k << 1);
    byte ^= (((row >> 1) ^ (row >> 3)) & 3) << 4;
    return byte >> 1;
}
// out-kernel swizzle (row stride 128 B)
__device__ __forceinline__ int bofs(int row, int k) {
    return (((row) << 7) | ((k) << 1)) ^ (((row ^ (row >> 2)) & 7) << 4);
}

// ---------------- K1: energy = v v^T (split-K, fp16 MFMA, depth-2 prefetch) ----
// Unchanged R6 pipeline; grid flattened to 1D with XCD-aware decode:
// XCD x handles batches {2x, 2x+1} -> energy atomics + v slabs XCD-local.
__global__ __launch_bounds__(1024) void gram_kernel(const float* __restrict__ x,
                                                    float* __restrict__ energy,
                                                    float* __restrict__ pooled) {
    int bid   = blockIdx.x;                 // 0..255
    int g     = (bid & 7) * 32 + (bid >> 3);
    int b     = g >> 4;
    int split = g & 15;
    const float* v = x + (size_t)b * CDIM * HW;
    int kbase0 = split * KSLAB;

    __shared__ _Float16 lds[2][CDIM * KCH];   // 2 x 16 KB

    int t    = threadIdx.x;
    int row  = t >> 2;
    int kq   = t & 3;
    int lane = t & 63;
    int wave = t >> 6;
    int wr   = wave >> 2, wc = wave & 3;
    int lhi  = lane >> 4, llo = lane & 15;

    const float4* vrow = (const float4*)(v + (size_t)row * HW);

    f32x4 acc[4][4];
    #pragma unroll
    for (int i = 0; i < 4; ++i)
        #pragma unroll
        for (int j = 0; j < 4; ++j)
            acc[i][j] = (f32x4){0.f, 0.f, 0.f, 0.f};

    float psum = 0.f;
    float4 fa0, fa1, fb0, fb1;

    {
        int kb0 = kbase0;
        fa0 = vrow[(kb0 >> 2) + kq * 2];
        fa1 = vrow[(kb0 >> 2) + kq * 2 + 1];
        int kb1 = kbase0 + KCH;
        fb0 = vrow[(kb1 >> 2) + kq * 2];
        fb1 = vrow[(kb1 >> 2) + kq * 2 + 1];
    }

    auto body = [&](float4& g0, float4& g1, _Float16* buf, int ch) {
        float vals[8] = { g0.x, g0.y, g0.z, g0.w, g1.x, g1.y, g1.z, g1.w };
        half8 h;
        #pragma unroll
        for (int j = 0; j < 8; ++j) {
            psum += vals[j];
            h[j] = (_Float16)vals[j];
        }
        *(half8*)&buf[gswz16(row, kq * 8)] = h;
        if (ch + 2 < NCH) {
            int kb = kbase0 + (ch + 2) * KCH;
            g0 = vrow[(kb >> 2) + kq * 2];
            g1 = vrow[(kb >> 2) + kq * 2 + 1];
        }
        lds_barrier();

        half8 A[4], B[4];
        #pragma unroll
        for (int rb = 0; rb < 4; ++rb)
            A[rb] = *(const half8*)&buf[gswz16(wr * 64 + rb * 16 + llo, lhi * 8)];
        #pragma unroll
        for (int cb = 0; cb < 4; ++cb)
            B[cb] = *(const half8*)&buf[gswz16(wc * 64 + cb * 16 + llo, lhi * 8)];

        __builtin_amdgcn_s_setprio(1);
        #pragma unroll
        for (int rb = 0; rb < 4; ++rb)
            #pragma unroll
            for (int cb = 0; cb < 4; ++cb)
                acc[rb][cb] = __builtin_amdgcn_mfma_f32_16x16x32_f16(A[rb], B[cb], acc[rb][cb], 0, 0, 0);
        __builtin_amdgcn_s_setprio(0);
    };

    #pragma unroll 1
    for (int it = 0; it < NCH / 2; ++it) {
        body(fa0, fa1, (_Float16*)lds[0], it * 2);
        body(fb0, fb1, (_Float16*)lds[1], it * 2 + 1);
    }

    psum += __shfl_xor(psum, 1);
    psum += __shfl_xor(psum, 2);
    if (kq == 0) atomicAdd(&pooled[b * CDIM + row], psum);

    #pragma unroll
    for (int rb = 0; rb < 4; ++rb) {
        int r0 = wr * 64 + rb * 16 + lhi * 4;
        #pragma unroll
        for (int cb = 0; cb < 4; ++cb) {
            int c0 = wc * 64 + cb * 16 + llo;
            #pragma unroll
            for (int reg = 0; reg < 4; ++reg)
                atomicAdd(&energy[((size_t)b * CDIM + r0 + reg) * CDIM + c0], acc[rb][cb][reg]);
        }
    }
}

// ---------------- K2: SE MLP -> sigmoid gate ----------------
__global__ __launch_bounds__(256) void se_kernel(const float* __restrict__ pooled,
                                                 const float* __restrict__ w1,
                                                 const float* __restrict__ b1,
                                                 const float* __restrict__ w2,
                                                 const float* __restrict__ b2,
                                                 float* __restrict__ gate) {
    int b = blockIdx.x;
    int t = threadIdx.x;
    __shared__ float p[CDIM];
    __shared__ float hid[RDIM];
    p[t] = pooled[b * CDIM + t] * (1.0f / HW);
    __syncthreads();
    if (t < RDIM) {
        float s = b1[t];
        const float* wr = w1 + t * CDIM;
        for (int k = 0; k < CDIM; ++k) s = fmaf(wr[k], p[k], s);
        hid[t] = s > 0.f ? s : 0.f;
    }
    __syncthreads();
    float s = b2[t];
    const float* wr = w2 + t * RDIM;
    #pragma unroll
    for (int k = 0; k < RDIM; ++k) s = fmaf(wr[k], hid[k], s);
    gate[b * CDIM + t] = 1.0f / (1.0f + expf(-s));
}

// ---------------- K3: row softmax of (rowmax - energy), in place ----------------
__global__ __launch_bounds__(256) void softmax_kernel(float* __restrict__ energy) {
    int row = blockIdx.x;
    float* e = energy + (size_t)row * CDIM;
    int t = threadIdx.x;
    float val = e[t];

    float m = val;
    for (int off = 32; off > 0; off >>= 1) m = fminf(m, __shfl_down(m, off));
    __shared__ float redm[4];
    if ((t & 63) == 0) redm[t >> 6] = m;
    __syncthreads();
    float rowmin = fminf(fminf(redm[0], redm[1]), fminf(redm[2], redm[3]));

    float p = expf(rowmin - val);
    float s = p;
    for (int off = 32; off > 0; off >>= 1) s += __shfl_down(s, off);
    __shared__ float reds[4];
    if ((t & 63) == 0) reds[t >> 6] = s;
    __syncthreads();
    float tot = reds[0] + reds[1] + reds[2] + reds[3];
    e[t] = p / tot;
}

// ---------------- K4: out = gamma * gate * (att @ v) + x  (bf16 MFMA) ----------
// v3: 512 thr (8 waves, 2n x 4c), tile 128n x 256c, 48 KB LDS -> 2 blocks/CU.
// XCD-aware 1D grid (1152 = 8 x 144): XCD x owns batches {2x,2x+1} -> att L2-hot.
// v^T prefetched in regs across chunks; att staged transiently from L2.
__global__ __launch_bounds__(512, 4) void out_kernel(const float* __restrict__ att,
                                                     const float* __restrict__ x,
                                                     const float* __restrict__ gate,
                                                     const float* __restrict__ gammap,
                                                     float* __restrict__ out) {
    __shared__ __align__(16) char lds[49152];   // att 32KB @0, v^T 16KB @VOFF

    const int bid  = blockIdx.x;                 // 0..1151
    const int g    = (bid & 7) * 144 + (bid >> 3);
    const int b    = g / NTILES;
    const int nblk = (g % NTILES) * BN;

    const int t    = threadIdx.x;
    const int lane = t & 63;
    const int wave = t >> 6;         // 0..7
    const int wn   = wave >> 2;      // 0..1  (n)
    const int wcc  = wave & 3;       // 0..3  (c)
    const int lhi  = lane >> 4, llo = lane & 15;

    const float* v    = x   + (size_t)b * CDIM * HW;
    const float* attb = att + (size_t)b * CDIM * CDIM;

    f32x4 acc[4][4];   // [rb over n][cb over c]
    #pragma unroll
    for (int i = 0; i < 4; ++i)
        #pragma unroll
        for (int j = 0; j < 4; ++j)
            acc[i][j] = (f32x4){0.f, 0.f, 0.f, 0.f};

    // v^T staging regs: thread owns dd-pair (2*ddp, 2*ddp+1), 2 n-quads.
    const int ddp = t >> 4;          // 0..31
    const int n4  = (t & 15) * 4;    // 0..60; second quad at +64
    float4 va0[2], va1[2];

    auto load_v = [&](int k0) {
        #pragma unroll
        for (int i = 0; i < 2; ++i) {
            const float* r0 = v + (size_t)(k0 + 2 * ddp) * HW + nblk + n4 + 64 * i;
            va0[i] = *(const float4*)r0;
            va1[i] = *(const float4*)(r0 + HW);
        }
    };

    load_v(0);

    for (int ch = 0; ch < 4; ++ch) {
        int k0 = ch * BK;
        __syncthreads();   // prior chunk's frag reads done
        // ---- v^T transpose-writes (pack2 -> u32) ----
        #pragma unroll
        for (int i = 0; i < 2; ++i) {
            const float* f0 = (const float*)&va0[i];
            const float* f1 = (const float*)&va1[i];
            #pragma unroll
            for (int j = 0; j < 4; ++j) {
                int n = n4 + 64 * i + j;
                *(unsigned*)(lds + VOFF + bofs(n, 2 * ddp)) = pack2(f0[j], f1[j]);
            }
        }
        // ---- att staged transiently (L2-hot with XCD swizzle) ----
        #pragma unroll
        for (int i = 0; i < 8; ++i) {
            int c = (t >> 4) + 32 * i;
            float4 a = *(const float4*)&attb[(size_t)c * CDIM + k0 + (t & 15) * 4];
            short4_t h = { (short)bf16_rne(a.x), (short)bf16_rne(a.y),
                           (short)bf16_rne(a.z), (short)bf16_rne(a.w) };
            *(short4_t*)(lds + bofs(c, (t & 15) * 4)) = h;
        }
        __syncthreads();   // tile staged

        if (ch < 3) load_v(k0 + BK);   // prefetch v under MFMA

        #pragma unroll
        for (int ks = 0; ks < 2; ++ks) {
            int kb = ks * 32 + lhi * 8;
            short8 An[4], Bc[4];
            #pragma unroll
            for (int rb = 0; rb < 4; ++rb)   // A = v^T rows (n, 0..127)
                An[rb] = *(const short8*)(lds + VOFF + bofs(wn * 64 + rb * 16 + llo, kb));
            #pragma unroll
            for (int cb = 0; cb < 4; ++cb)   // B = att rows (c, 0..255)
                Bc[cb] = *(const short8*)(lds + bofs(wcc * 64 + cb * 16 + llo, kb));
            #pragma unroll
            for (int rb = 0; rb < 4; ++rb)
                #pragma unroll
                for (int cb = 0; cb < 4; ++cb)
                    acc[rb][cb] = __builtin_amdgcn_mfma_f32_16x16x32_bf16(An[rb], Bc[cb], acc[rb][cb], 0, 0, 0);
        }
    }

    // ---- epilogue: lane owns col c, 4 consecutive n -> float4 ----
    float gm = gammap[0];
    float gv[4];
    #pragma unroll
    for (int cb = 0; cb < 4; ++cb)
        gv[cb] = gm * gate[b * CDIM + wcc * 64 + cb * 16 + llo];

    #pragma unroll
    for (int rb = 0; rb < 4; ++rb) {
        int n0 = wn * 64 + rb * 16 + lhi * 4;
        #pragma unroll
        for (int cb = 0; cb < 4; ++cb) {
            int c = wcc * 64 + cb * 16 + llo;
            size_t base = ((size_t)b * CDIM + c) * HW + nblk + n0;
            float4 xv = *(const float4*)&x[base];
            float4 o;
            o.x = fmaf(acc[rb][cb][0], gv[cb], xv.x);
            o.y = fmaf(acc[rb][cb][1], gv[cb], xv.y);
            o.z = fmaf(acc[rb][cb][2], gv[cb], xv.z);
            o.w = fmaf(acc[rb][cb][3], gv[cb], xv.w);
            *(float4*)&out[base] = o;
        }
    }
}

extern "C" void kernel_launch(void* const* d_in, const int* in_sizes, int n_in,
                              void* d_out, int out_size, void* d_ws, size_t ws_size,
                              hipStream_t stream) {
    const float* x     = (const float*)d_in[0];
    const float* gamma = (const float*)d_in[1];
    const float* w1    = (const float*)d_in[2];
    const float* b1    = (const float*)d_in[3];
    const float* w2    = (const float*)d_in[4];
    const float* b2    = (const float*)d_in[5];
    float* out = (float*)d_out;

    float* energy = (float*)d_ws;                                // B*C*C = 4 MB
    float* pooled = energy + (size_t)BATCH * CDIM * CDIM;
    float* gate   = pooled + BATCH * CDIM;

    hipMemsetAsync(energy, 0, (size_t)BATCH * CDIM * CDIM * sizeof(float), stream);
    hipMemsetAsync(pooled, 0, (size_t)BATCH * CDIM * sizeof(float), stream);
    gram_kernel<<<SPLITS * BATCH, 1024, 0, stream>>>(x, energy, pooled);
    se_kernel<<<BATCH, 256, 0, stream>>>(pooled, w1, b1, w2, b2, gate);
    softmax_kernel<<<BATCH * CDIM, 256, 0, stream>>>(energy);
    out_kernel<<<NTILES * BATCH, 512, 0, stream>>>(energy, x, gate, gamma, out);
}

// Round 10
// 215.156 us; speedup vs baseline: 1.5995x; 1.5995x over previous
//
#include <hip/hip_runtime.h>
#include <math.h>

#define BATCH 16
#define CDIM 256
#define HW 9216
#define RDIM 32
#define SPLITS 16
#define KSLAB (HW / SPLITS)   /* 576 */
#define KCH 32                /* gram k-columns per chunk */
#define NCH (KSLAB / KCH)     /* 18, even */

#define BN 256                /* out_kernel n-tile */
#define BK 64                 /* out_kernel k-chunk */
#define VOFF 32768            /* v^T tile byte offset inside shared block */

typedef __attribute__((ext_vector_type(8))) short short8;
typedef __attribute__((ext_vector_type(4))) short short4_t;
typedef __attribute__((ext_vector_type(4))) float f32x4;
typedef __attribute__((ext_vector_type(8))) _Float16 half8;

__device__ __forceinline__ unsigned short bf16_rne(float x) {
    union { float f; unsigned u; } a; a.f = x;
    return (unsigned short)((a.u + 0x7fffu + ((a.u >> 16) & 1u)) >> 16);
}
__device__ __forceinline__ unsigned pack2(float lo, float hi) {
    return (unsigned)bf16_rne(lo) | ((unsigned)bf16_rne(hi) << 16);
}

// Non-draining barrier: ds ops visible, global loads STAY IN FLIGHT (gram only).
__device__ __forceinline__ void lds_barrier() {
    asm volatile("s_waitcnt lgkmcnt(0)" ::: "memory");
    __builtin_amdgcn_s_barrier();
}

// async 16B global->LDS copy
__device__ __forceinline__ void gload16(const void* g, void* l) {
    __builtin_amdgcn_global_load_lds(
        (const __attribute__((address_space(1))) unsigned*)g,
        (__attribute__((address_space(3))) unsigned*)l, 16, 0, 0);
}

// gram fp16 tile [256 rows][32 k], row stride 64 B (2-way max conflicts).
__device__ __forceinline__ int gswz16(int row, int k) {
    int byte = (row << 6) + (k << 1);
    byte ^= (((row >> 1) ^ (row >> 3)) & 3) << 4;
    return byte >> 1;
}
// out-kernel swizzle (row stride 128 B); byte offset in a [256][64] bf16 tile.
__device__ __forceinline__ int bofs(int row, int k) {
    return (((row) << 7) | ((k) << 1)) ^ (((row ^ (row >> 2)) & 7) << 4);
}

// ---------------- K1: energy = v v^T (split-K, fp16 MFMA, depth-2 prefetch) ----
// R6-proven pipeline, R8 2D grid.
__global__ __launch_bounds__(1024) void gram_kernel(const float* __restrict__ x,
                                                    float* __restrict__ energy,
                                                    float* __restrict__ pooled) {
    int split = blockIdx.x;
    int b     = blockIdx.y;
    const float* v = x + (size_t)b * CDIM * HW;
    int kbase0 = split * KSLAB;

    __shared__ _Float16 lds[2][CDIM * KCH];   // 2 x 16 KB

    int t    = threadIdx.x;
    int row  = t >> 2;
    int kq   = t & 3;
    int lane = t & 63;
    int wave = t >> 6;
    int wr   = wave >> 2, wc = wave & 3;
    int lhi  = lane >> 4, llo = lane & 15;

    const float4* vrow = (const float4*)(v + (size_t)row * HW);

    f32x4 acc[4][4];
    #pragma unroll
    for (int i = 0; i < 4; ++i)
        #pragma unroll
        for (int j = 0; j < 4; ++j)
            acc[i][j] = (f32x4){0.f, 0.f, 0.f, 0.f};

    float psum = 0.f;
    float4 fa0, fa1, fb0, fb1;

    {
        int kb0 = kbase0;
        fa0 = vrow[(kb0 >> 2) + kq * 2];
        fa1 = vrow[(kb0 >> 2) + kq * 2 + 1];
        int kb1 = kbase0 + KCH;
        fb0 = vrow[(kb1 >> 2) + kq * 2];
        fb1 = vrow[(kb1 >> 2) + kq * 2 + 1];
    }

    auto body = [&](float4& g0, float4& g1, _Float16* buf, int ch) {
        float vals[8] = { g0.x, g0.y, g0.z, g0.w, g1.x, g1.y, g1.z, g1.w };
        half8 h;
        #pragma unroll
        for (int j = 0; j < 8; ++j) {
            psum += vals[j];
            h[j] = (_Float16)vals[j];
        }
        *(half8*)&buf[gswz16(row, kq * 8)] = h;
        if (ch + 2 < NCH) {
            int kb = kbase0 + (ch + 2) * KCH;
            g0 = vrow[(kb >> 2) + kq * 2];
            g1 = vrow[(kb >> 2) + kq * 2 + 1];
        }
        lds_barrier();

        half8 A[4], B[4];
        #pragma unroll
        for (int rb = 0; rb < 4; ++rb)
            A[rb] = *(const half8*)&buf[gswz16(wr * 64 + rb * 16 + llo, lhi * 8)];
        #pragma unroll
        for (int cb = 0; cb < 4; ++cb)
            B[cb] = *(const half8*)&buf[gswz16(wc * 64 + cb * 16 + llo, lhi * 8)];

        __builtin_amdgcn_s_setprio(1);
        #pragma unroll
        for (int rb = 0; rb < 4; ++rb)
            #pragma unroll
            for (int cb = 0; cb < 4; ++cb)
                acc[rb][cb] = __builtin_amdgcn_mfma_f32_16x16x32_f16(A[rb], B[cb], acc[rb][cb], 0, 0, 0);
        __builtin_amdgcn_s_setprio(0);
    };

    #pragma unroll 1
    for (int it = 0; it < NCH / 2; ++it) {
        body(fa0, fa1, (_Float16*)lds[0], it * 2);
        body(fb0, fb1, (_Float16*)lds[1], it * 2 + 1);
    }

    psum += __shfl_xor(psum, 1);
    psum += __shfl_xor(psum, 2);
    if (kq == 0) atomicAdd(&pooled[b * CDIM + row], psum);

    #pragma unroll
    for (int rb = 0; rb < 4; ++rb) {
        int r0 = wr * 64 + rb * 16 + lhi * 4;
        #pragma unroll
        for (int cb = 0; cb < 4; ++cb) {
            int c0 = wc * 64 + cb * 16 + llo;
            #pragma unroll
            for (int reg = 0; reg < 4; ++reg)
                atomicAdd(&energy[((size_t)b * CDIM + r0 + reg) * CDIM + c0], acc[rb][cb][reg]);
        }
    }
}

// ---------------- K2: SE MLP -> sigmoid gate ----------------
__global__ __launch_bounds__(256) void se_kernel(const float* __restrict__ pooled,
                                                 const float* __restrict__ w1,
                                                 const float* __restrict__ b1,
                                                 const float* __restrict__ w2,
                                                 const float* __restrict__ b2,
                                                 float* __restrict__ gate) {
    int b = blockIdx.x;
    int t = threadIdx.x;
    __shared__ float p[CDIM];
    __shared__ float hid[RDIM];
    p[t] = pooled[b * CDIM + t] * (1.0f / HW);
    __syncthreads();
    if (t < RDIM) {
        float s = b1[t];
        const float* wr = w1 + t * CDIM;
        for (int k = 0; k < CDIM; ++k) s = fmaf(wr[k], p[k], s);
        hid[t] = s > 0.f ? s : 0.f;
    }
    __syncthreads();
    float s = b2[t];
    const float* wr = w2 + t * RDIM;
    #pragma unroll
    for (int k = 0; k < RDIM; ++k) s = fmaf(wr[k], hid[k], s);
    gate[b * CDIM + t] = 1.0f / (1.0f + expf(-s));
}

// ---------------- K3: softmax -> bf16 att in PRE-SWIZZLED chunk-image layout ----
// att image per batch: 4 chunks x 32KB; chunk ch holds d in [ch*64,(ch+1)*64),
// byte (within chunk) = bofs(c, d&63). out_kernel memcpys each chunk into LDS
// via global_load_lds and reads frags with bofs -- identical image.
__global__ __launch_bounds__(256) void softmax_kernel(const float* __restrict__ energy,
                                                      unsigned short* __restrict__ atts) {
    int row = blockIdx.x;              // b*C + c
    int b = row >> 8, c = row & 255;
    const float* e = energy + (size_t)row * CDIM;
    int t = threadIdx.x;               // t = d
    float val = e[t];

    float m = val;
    for (int off = 32; off > 0; off >>= 1) m = fminf(m, __shfl_down(m, off));
    __shared__ float redm[4];
    if ((t & 63) == 0) redm[t >> 6] = m;
    __syncthreads();
    float rowmin = fminf(fminf(redm[0], redm[1]), fminf(redm[2], redm[3]));

    float p = expf(rowmin - val);
    float s = p;
    for (int off = 32; off > 0; off >>= 1) s += __shfl_down(s, off);
    __shared__ float reds[4];
    if ((t & 63) == 0) reds[t >> 6] = s;
    __syncthreads();
    float tot = reds[0] + reds[1] + reds[2] + reds[3];

    size_t idx = (size_t)b * 65536 + (size_t)(t >> 6) * 16384 + (bofs(c, t & 63) >> 1);
    atts[idx] = bf16_rne(p / tot);
}

// ---------------- K4: out = gamma * gate * (att @ v) + x  (bf16 MFMA) ----------
// R8-proven structure; att staged via 2x global_load_lds (pre-swizzled bf16).
__global__ __launch_bounds__(1024) void out_kernel(const unsigned short* __restrict__ atts,
                                                   const float* __restrict__ x,
                                                   const float* __restrict__ gate,
                                                   const float* __restrict__ gammap,
                                                   float* __restrict__ out) {
    __shared__ __align__(16) char lds[65536];   // att 32KB @0, v^T 32KB @VOFF

    const int t    = threadIdx.x;
    const int lane = t & 63;
    const int wave = t >> 6;
    const int wn   = wave >> 2;      // wave n-index (0..3)
    const int wcc  = wave & 3;       // wave c-index (0..3)
    const int lhi  = lane >> 4, llo = lane & 15;
    const int nblk = blockIdx.x * BN;
    const int b    = blockIdx.y;

    const float* v     = x + (size_t)b * CDIM * HW;
    const char*  attsB = (const char*)atts + (size_t)b * 131072;

    f32x4 acc[4][4];   // [rb over n][cb over c]
    #pragma unroll
    for (int i = 0; i < 4; ++i)
        #pragma unroll
        for (int j = 0; j < 4; ++j)
            acc[i][j] = (f32x4){0.f, 0.f, 0.f, 0.f};

    float4 va0[2], va1[2];

    auto load_v = [&](int k0) {
        #pragma unroll
        for (int i = 0; i < 2; ++i) {
            int dd0 = 2 * (wave + 16 * i);
            const float* r0 = v + (size_t)(k0 + dd0) * HW + nblk + lane * 4;
            va0[i] = *(const float4*)r0;
            va1[i] = *(const float4*)(r0 + HW);
        }
    };

    load_v(0);

    for (int ch = 0; ch < 4; ++ch) {
        __syncthreads();   // prior chunk's frag reads done (drains everything)
        // ---- att chunk: 32KB straight memcpy HBM/L2 -> LDS, in flight under stage
        gload16(attsB + ch * 32768 + t * 16, lds + t * 16);
        gload16(attsB + ch * 32768 + 16384 + t * 16, lds + 16384 + t * 16);
        // ---- v^T transpose-writes (pack2 -> u32) ----
        #pragma unroll
        for (int i = 0; i < 2; ++i) {
            int dd0 = 2 * (wave + 16 * i);
            const float* f0 = (const float*)&va0[i];
            const float* f1 = (const float*)&va1[i];
            #pragma unroll
            for (int j = 0; j < 4; ++j) {
                int n = lane * 4 + j;
                *(unsigned*)(lds + VOFF + bofs(n, dd0)) = pack2(f0[j], f1[j]);
            }
        }
        __syncthreads();   // tile staged (att gloads + v ds_writes drained)

        if (ch < 3) load_v((ch + 1) * BK);   // prefetch v under MFMA

        #pragma unroll
        for (int ks = 0; ks < 2; ++ks) {
            int kb = ks * 32 + lhi * 8;
            short8 An[4], Bc[4];
            #pragma unroll
            for (int rb = 0; rb < 4; ++rb)   // A = v^T rows (n)
                An[rb] = *(const short8*)(lds + VOFF + bofs(wn * 64 + rb * 16 + llo, kb));
            #pragma unroll
            for (int cb = 0; cb < 4; ++cb)   // B = att rows (c)
                Bc[cb] = *(const short8*)(lds + bofs(wcc * 64 + cb * 16 + llo, kb));
            #pragma unroll
            for (int rb = 0; rb < 4; ++rb)
                #pragma unroll
                for (int cb = 0; cb < 4; ++cb)
                    acc[rb][cb] = __builtin_amdgcn_mfma_f32_16x16x32_bf16(An[rb], Bc[cb], acc[rb][cb], 0, 0, 0);
        }
    }

    // ---- epilogue: lane owns col c, 4 consecutive n -> float4 ----
    float gm = gammap[0];
    float gv[4];
    #pragma unroll
    for (int cb = 0; cb < 4; ++cb)
        gv[cb] = gm * gate[b * CDIM + wcc * 64 + cb * 16 + llo];

    #pragma unroll
    for (int rb = 0; rb < 4; ++rb) {
        int n0 = wn * 64 + rb * 16 + lhi * 4;
        #pragma unroll
        for (int cb = 0; cb < 4; ++cb) {
            int c = wcc * 64 + cb * 16 + llo;
            size_t base = ((size_t)b * CDIM + c) * HW + nblk + n0;
            float4 xv = *(const float4*)&x[base];
            float4 o;
            o.x = fmaf(acc[rb][cb][0], gv[cb], xv.x);
            o.y = fmaf(acc[rb][cb][1], gv[cb], xv.y);
            o.z = fmaf(acc[rb][cb][2], gv[cb], xv.z);
            o.w = fmaf(acc[rb][cb][3], gv[cb], xv.w);
            *(float4*)&out[base] = o;
        }
    }
}

extern "C" void kernel_launch(void* const* d_in, const int* in_sizes, int n_in,
                              void* d_out, int out_size, void* d_ws, size_t ws_size,
                              hipStream_t stream) {
    const float* x     = (const float*)d_in[0];
    const float* gamma = (const float*)d_in[1];
    const float* w1    = (const float*)d_in[2];
    const float* b1    = (const float*)d_in[3];
    const float* w2    = (const float*)d_in[4];
    const float* b2    = (const float*)d_in[5];
    float* out = (float*)d_out;

    float*          energy = (float*)d_ws;                              // 4 MB
    unsigned short* atts   = (unsigned short*)(energy + (size_t)BATCH * CDIM * CDIM); // 2 MB
    float*          pooled = (float*)(atts + (size_t)BATCH * CDIM * CDIM);
    float*          gate   = pooled + BATCH * CDIM;

    hipMemsetAsync(energy, 0, (size_t)BATCH * CDIM * CDIM * sizeof(float), stream);
    hipMemsetAsync(pooled, 0, (size_t)BATCH * CDIM * sizeof(float), stream);
    gram_kernel<<<dim3(SPLITS, BATCH), 1024, 0, stream>>>(x, energy, pooled);
    se_kernel<<<BATCH, 256, 0, stream>>>(pooled, w1, b1, w2, b2, gate);
    softmax_kernel<<<BATCH * CDIM, 256, 0, stream>>>(energy, atts);
    out_kernel<<<dim3(HW / BN, BATCH), 1024, 0, stream>>>(atts, x, gate, gamma, out);
}

// Round 11
// 207.401 us; speedup vs baseline: 1.6593x; 1.0374x over previous
//
#include <hip/hip_runtime.h>
#include <math.h>

#define BATCH 16
#define CDIM 256
#define HW 9216
#define RDIM 32
#define SPLITS 16
#define KSLAB (HW / SPLITS)   /* 576 */
#define KCH 32                /* gram k-columns per chunk */
#define NCH (KSLAB / KCH)     /* 18, even */

#define BN 128                /* out_kernel n-tile */
#define BK 64                 /* out_kernel k-chunk */
#define VOFF 32768            /* v^T tile byte offset inside shared block */

typedef __attribute__((ext_vector_type(8))) short short8;
typedef __attribute__((ext_vector_type(4))) short short4_t;
typedef __attribute__((ext_vector_type(4))) float f32x4;
typedef __attribute__((ext_vector_type(8))) _Float16 half8;

__device__ __forceinline__ unsigned short bf16_rne(float x) {
    union { float f; unsigned u; } a; a.f = x;
    return (unsigned short)((a.u + 0x7fffu + ((a.u >> 16) & 1u)) >> 16);
}
__device__ __forceinline__ unsigned pack2(float lo, float hi) {
    return (unsigned)bf16_rne(lo) | ((unsigned)bf16_rne(hi) << 16);
}

// Non-draining barrier: ds ops visible, global loads STAY IN FLIGHT (gram only).
__device__ __forceinline__ void lds_barrier() {
    asm volatile("s_waitcnt lgkmcnt(0)" ::: "memory");
    __builtin_amdgcn_s_barrier();
}

// async 16B global->LDS copy
__device__ __forceinline__ void gload16(const void* g, void* l) {
    __builtin_amdgcn_global_load_lds(
        (const __attribute__((address_space(1))) unsigned*)g,
        (__attribute__((address_space(3))) unsigned*)l, 16, 0, 0);
}

// gram fp16 tile [256 rows][32 k], row stride 64 B (2-way max conflicts).
__device__ __forceinline__ int gswz16(int row, int k) {
    int byte = (row << 6) + (k << 1);
    byte ^= (((row >> 1) ^ (row >> 3)) & 3) << 4;
    return byte >> 1;
}
// out-kernel swizzle (row stride 128 B); byte offset in a [*][64] bf16 tile.
__device__ __forceinline__ int bofs(int row, int k) {
    return (((row) << 7) | ((k) << 1)) ^ (((row ^ (row >> 2)) & 7) << 4);
}

// ---------------- K1: energy = v v^T (split-K, fp16 MFMA, depth-2 prefetch) ----
// R6-proven pipeline, R8 2D grid. UNCHANGED from R10.
__global__ __launch_bounds__(1024) void gram_kernel(const float* __restrict__ x,
                                                    float* __restrict__ energy,
                                                    float* __restrict__ pooled) {
    int split = blockIdx.x;
    int b     = blockIdx.y;
    const float* v = x + (size_t)b * CDIM * HW;
    int kbase0 = split * KSLAB;

    __shared__ _Float16 lds[2][CDIM * KCH];   // 2 x 16 KB

    int t    = threadIdx.x;
    int row  = t >> 2;
    int kq   = t & 3;
    int lane = t & 63;
    int wave = t >> 6;
    int wr   = wave >> 2, wc = wave & 3;
    int lhi  = lane >> 4, llo = lane & 15;

    const float4* vrow = (const float4*)(v + (size_t)row * HW);

    f32x4 acc[4][4];
    #pragma unroll
    for (int i = 0; i < 4; ++i)
        #pragma unroll
        for (int j = 0; j < 4; ++j)
            acc[i][j] = (f32x4){0.f, 0.f, 0.f, 0.f};

    float psum = 0.f;
    float4 fa0, fa1, fb0, fb1;

    {
        int kb0 = kbase0;
        fa0 = vrow[(kb0 >> 2) + kq * 2];
        fa1 = vrow[(kb0 >> 2) + kq * 2 + 1];
        int kb1 = kbase0 + KCH;
        fb0 = vrow[(kb1 >> 2) + kq * 2];
        fb1 = vrow[(kb1 >> 2) + kq * 2 + 1];
    }

    auto body = [&](float4& g0, float4& g1, _Float16* buf, int ch) {
        float vals[8] = { g0.x, g0.y, g0.z, g0.w, g1.x, g1.y, g1.z, g1.w };
        half8 h;
        #pragma unroll
        for (int j = 0; j < 8; ++j) {
            psum += vals[j];
            h[j] = (_Float16)vals[j];
        }
        *(half8*)&buf[gswz16(row, kq * 8)] = h;
        if (ch + 2 < NCH) {
            int kb = kbase0 + (ch + 2) * KCH;
            g0 = vrow[(kb >> 2) + kq * 2];
            g1 = vrow[(kb >> 2) + kq * 2 + 1];
        }
        lds_barrier();

        half8 A[4], B[4];
        #pragma unroll
        for (int rb = 0; rb < 4; ++rb)
            A[rb] = *(const half8*)&buf[gswz16(wr * 64 + rb * 16 + llo, lhi * 8)];
        #pragma unroll
        for (int cb = 0; cb < 4; ++cb)
            B[cb] = *(const half8*)&buf[gswz16(wc * 64 + cb * 16 + llo, lhi * 8)];

        __builtin_amdgcn_s_setprio(1);
        #pragma unroll
        for (int rb = 0; rb < 4; ++rb)
            #pragma unroll
            for (int cb = 0; cb < 4; ++cb)
                acc[rb][cb] = __builtin_amdgcn_mfma_f32_16x16x32_f16(A[rb], B[cb], acc[rb][cb], 0, 0, 0);
        __builtin_amdgcn_s_setprio(0);
    };

    #pragma unroll 1
    for (int it = 0; it < NCH / 2; ++it) {
        body(fa0, fa1, (_Float16*)lds[0], it * 2);
        body(fb0, fb1, (_Float16*)lds[1], it * 2 + 1);
    }

    psum += __shfl_xor(psum, 1);
    psum += __shfl_xor(psum, 2);
    if (kq == 0) atomicAdd(&pooled[b * CDIM + row], psum);

    #pragma unroll
    for (int rb = 0; rb < 4; ++rb) {
        int r0 = wr * 64 + rb * 16 + lhi * 4;
        #pragma unroll
        for (int cb = 0; cb < 4; ++cb) {
            int c0 = wc * 64 + cb * 16 + llo;
            #pragma unroll
            for (int reg = 0; reg < 4; ++reg)
                atomicAdd(&energy[((size_t)b * CDIM + r0 + reg) * CDIM + c0], acc[rb][cb][reg]);
        }
    }
}

// ---------------- K2: SE MLP -> sigmoid gate ----------------
__global__ __launch_bounds__(256) void se_kernel(const float* __restrict__ pooled,
                                                 const float* __restrict__ w1,
                                                 const float* __restrict__ b1,
                                                 const float* __restrict__ w2,
                                                 const float* __restrict__ b2,
                                                 float* __restrict__ gate) {
    int b = blockIdx.x;
    int t = threadIdx.x;
    __shared__ float p[CDIM];
    __shared__ float hid[RDIM];
    p[t] = pooled[b * CDIM + t] * (1.0f / HW);
    __syncthreads();
    if (t < RDIM) {
        float s = b1[t];
        const float* wr = w1 + t * CDIM;
        for (int k = 0; k < CDIM; ++k) s = fmaf(wr[k], p[k], s);
        hid[t] = s > 0.f ? s : 0.f;
    }
    __syncthreads();
    float s = b2[t];
    const float* wr = w2 + t * RDIM;
    #pragma unroll
    for (int k = 0; k < RDIM; ++k) s = fmaf(wr[k], hid[k], s);
    gate[b * CDIM + t] = 1.0f / (1.0f + expf(-s));
}

// ---------------- K3: softmax -> bf16 att in PRE-SWIZZLED chunk-image layout ----
// UNCHANGED from R10.
__global__ __launch_bounds__(256) void softmax_kernel(const float* __restrict__ energy,
                                                      unsigned short* __restrict__ atts) {
    int row = blockIdx.x;              // b*C + c
    int b = row >> 8, c = row & 255;
    const float* e = energy + (size_t)row * CDIM;
    int t = threadIdx.x;               // t = d
    float val = e[t];

    float m = val;
    for (int off = 32; off > 0; off >>= 1) m = fminf(m, __shfl_down(m, off));
    __shared__ float redm[4];
    if ((t & 63) == 0) redm[t >> 6] = m;
    __syncthreads();
    float rowmin = fminf(fminf(redm[0], redm[1]), fminf(redm[2], redm[3]));

    float p = expf(rowmin - val);
    float s = p;
    for (int off = 32; off > 0; off >>= 1) s += __shfl_down(s, off);
    __shared__ float reds[4];
    if ((t & 63) == 0) reds[t >> 6] = s;
    __syncthreads();
    float tot = reds[0] + reds[1] + reds[2] + reds[3];

    size_t idx = (size_t)b * 65536 + (size_t)(t >> 6) * 16384 + (bofs(c, t & 63) >> 1);
    atts[idx] = bf16_rne(p / tot);
}

// ---------------- K4: out = gamma * gate * (att @ v) + x  (bf16 MFMA) ----------
// v4: 512 thr (8 waves, 2n x 4c), tile 128n x 256c, 48 KB LDS -> 2 blocks/CU
// (two independent barrier groups: one block's loads fly under the other's
// MFMA/drain -> ~2x time-averaged bytes in flight). Natural 2D grid.
// att staged via 4x global_load_lds (pre-swizzled bf16 image, R10-proven).
__global__ __launch_bounds__(512, 4) void out_kernel(const unsigned short* __restrict__ atts,
                                                     const float* __restrict__ x,
                                                     const float* __restrict__ gate,
                                                     const float* __restrict__ gammap,
                                                     float* __restrict__ out) {
    __shared__ __align__(16) char lds[49152];   // att 32KB @0, v^T 16KB @VOFF

    const int t    = threadIdx.x;
    const int lane = t & 63;
    const int wave = t >> 6;         // 0..7
    const int wn   = wave >> 2;      // 0..1  (n)
    const int wcc  = wave & 3;       // 0..3  (c)
    const int lhi  = lane >> 4, llo = lane & 15;
    const int nblk = blockIdx.x * BN;
    const int b    = blockIdx.y;

    const float* v     = x + (size_t)b * CDIM * HW;
    const char*  attsB = (const char*)atts + (size_t)b * 131072;

    f32x4 acc[4][4];   // [rb over n][cb over c]
    #pragma unroll
    for (int i = 0; i < 4; ++i)
        #pragma unroll
        for (int j = 0; j < 4; ++j)
            acc[i][j] = (f32x4){0.f, 0.f, 0.f, 0.f};

    // v^T staging: thread owns dd-pair (2*ddp, 2*ddp+1) at 4 consecutive n.
    const int ddp = t >> 4;          // 0..31
    const int n4  = (t & 15) * 4;    // 0..60; second quad at +64
    float4 va0[2], va1[2];

    auto load_v = [&](int k0) {
        #pragma unroll
        for (int i = 0; i < 2; ++i) {
            const float* r0 = v + (size_t)(k0 + 2 * ddp) * HW + nblk + n4 + 64 * i;
            va0[i] = *(const float4*)r0;
            va1[i] = *(const float4*)(r0 + HW);
        }
    };

    load_v(0);

    for (int ch = 0; ch < 4; ++ch) {
        __syncthreads();   // prior chunk's frag reads done
        // ---- att chunk: 32KB async memcpy -> LDS (in flight under v staging)
        #pragma unroll
        for (int i = 0; i < 4; ++i)
            gload16(attsB + ch * 32768 + i * 8192 + t * 16, lds + i * 8192 + t * 16);
        // ---- v^T transpose-writes (pack2 -> u32) ----
        #pragma unroll
        for (int i = 0; i < 2; ++i) {
            const float* f0 = (const float*)&va0[i];
            const float* f1 = (const float*)&va1[i];
            #pragma unroll
            for (int j = 0; j < 4; ++j) {
                int n = n4 + 64 * i + j;
                *(unsigned*)(lds + VOFF + bofs(n, 2 * ddp)) = pack2(f0[j], f1[j]);
            }
        }
        __syncthreads();   // tile staged (att gloads + v ds_writes drained)

        if (ch < 3) load_v((ch + 1) * BK);   // prefetch v under MFMA

        #pragma unroll
        for (int ks = 0; ks < 2; ++ks) {
            int kb = ks * 32 + lhi * 8;
            short8 An[4], Bc[4];
            #pragma unroll
            for (int rb = 0; rb < 4; ++rb)   // A = v^T rows (n, 0..127)
                An[rb] = *(const short8*)(lds + VOFF + bofs(wn * 64 + rb * 16 + llo, kb));
            #pragma unroll
            for (int cb = 0; cb < 4; ++cb)   // B = att rows (c, 0..255)
                Bc[cb] = *(const short8*)(lds + bofs(wcc * 64 + cb * 16 + llo, kb));
            #pragma unroll
            for (int rb = 0; rb < 4; ++rb)
                #pragma unroll
                for (int cb = 0; cb < 4; ++cb)
                    acc[rb][cb] = __builtin_amdgcn_mfma_f32_16x16x32_bf16(An[rb], Bc[cb], acc[rb][cb], 0, 0, 0);
        }
    }

    // ---- epilogue: lane owns col c, 4 consecutive n -> float4 ----
    float gm = gammap[0];
    float gv[4];
    #pragma unroll
    for (int cb = 0; cb < 4; ++cb)
        gv[cb] = gm * gate[b * CDIM + wcc * 64 + cb * 16 + llo];

    #pragma unroll
    for (int rb = 0; rb < 4; ++rb) {
        int n0 = wn * 64 + rb * 16 + lhi * 4;
        #pragma unroll
        for (int cb = 0; cb < 4; ++cb) {
            int c = wcc * 64 + cb * 16 + llo;
            size_t base = ((size_t)b * CDIM + c) * HW + nblk + n0;
            float4 xv = *(const float4*)&x[base];
            float4 o;
            o.x = fmaf(acc[rb][cb][0], gv[cb], xv.x);
            o.y = fmaf(acc[rb][cb][1], gv[cb], xv.y);
            o.z = fmaf(acc[rb][cb][2], gv[cb], xv.z);
            o.w = fmaf(acc[rb][cb][3], gv[cb], xv.w);
            *(float4*)&out[base] = o;
        }
    }
}

extern "C" void kernel_launch(void* const* d_in, const int* in_sizes, int n_in,
                              void* d_out, int out_size, void* d_ws, size_t ws_size,
                              hipStream_t stream) {
    const float* x     = (const float*)d_in[0];
    const float* gamma = (const float*)d_in[1];
    const float* w1    = (const float*)d_in[2];
    const float* b1    = (const float*)d_in[3];
    const float* w2    = (const float*)d_in[4];
    const float* b2    = (const float*)d_in[5];
    float* out = (float*)d_out;

    float*          energy = (float*)d_ws;                              // 4 MB
    unsigned short* atts   = (unsigned short*)(energy + (size_t)BATCH * CDIM * CDIM); // 2 MB
    float*          pooled = (float*)(atts + (size_t)BATCH * CDIM * CDIM);
    float*          gate   = pooled + BATCH * CDIM;

    hipMemsetAsync(energy, 0, (size_t)BATCH * CDIM * CDIM * sizeof(float), stream);
    hipMemsetAsync(pooled, 0, (size_t)BATCH * CDIM * sizeof(float), stream);
    gram_kernel<<<dim3(SPLITS, BATCH), 1024, 0, stream>>>(x, energy, pooled);
    se_kernel<<<BATCH, 256, 0, stream>>>(pooled, w1, b1, w2, b2, gate);
    softmax_kernel<<<BATCH * CDIM, 256, 0, stream>>>(energy, atts);
    out_kernel<<<dim3(HW / BN, BATCH), 512, 0, stream>>>(atts, x, gate, gamma, out);
}

// Round 12
// 189.589 us; speedup vs baseline: 1.8152x; 1.0940x over previous
//
#include <hip/hip_runtime.h>
#include <math.h>

#define BATCH 16
#define CDIM 256
#define HW 9216
#define RDIM 32
#define SPLITS 16
#define KSLAB (HW / SPLITS)   /* 576 */
#define KCH 32                /* gram k-columns per chunk */
#define NCH (KSLAB / KCH)     /* 18, even */

#define BN 128                /* out_kernel n-tile */
#define BK 64                 /* out_kernel k-chunk */
#define VOFF 32768            /* v^T tile byte offset inside shared block */

typedef __attribute__((ext_vector_type(8))) short short8;
typedef __attribute__((ext_vector_type(4))) short short4_t;
typedef __attribute__((ext_vector_type(4))) float f32x4;
typedef __attribute__((ext_vector_type(8))) _Float16 half8;

__device__ __forceinline__ unsigned short bf16_rne(float x) {
    union { float f; unsigned u; } a; a.f = x;
    return (unsigned short)((a.u + 0x7fffu + ((a.u >> 16) & 1u)) >> 16);
}
__device__ __forceinline__ unsigned pack2(float lo, float hi) {
    return (unsigned)bf16_rne(lo) | ((unsigned)bf16_rne(hi) << 16);
}

// Non-draining barrier: ds ops visible, global loads STAY IN FLIGHT (gram only).
__device__ __forceinline__ void lds_barrier() {
    asm volatile("s_waitcnt lgkmcnt(0)" ::: "memory");
    __builtin_amdgcn_s_barrier();
}

// async 16B global->LDS copy
__device__ __forceinline__ void gload16(const void* g, void* l) {
    __builtin_amdgcn_global_load_lds(
        (const __attribute__((address_space(1))) unsigned*)g,
        (__attribute__((address_space(3))) unsigned*)l, 16, 0, 0);
}

// gram fp16 tile [256 rows][32 k], row stride 64 B (2-way max conflicts).
__device__ __forceinline__ int gswz16(int row, int k) {
    int byte = (row << 6) + (k << 1);
    byte ^= (((row >> 1) ^ (row >> 3)) & 3) << 4;
    return byte >> 1;
}
// out-kernel swizzle (row stride 128 B); byte offset in a [*][64] bf16 tile.
__device__ __forceinline__ int bofs(int row, int k) {
    return (((row) << 7) | ((k) << 1)) ^ (((row ^ (row >> 2)) & 7) << 4);
}

// ---------------- K1: energy partials = v v^T (split-K, fp16 MFMA) ----------
// R6-proven pipeline. Epilogue: ATOMIC=false -> plain fp32 stores of this
// split's partial tile into part[split][b] (disjoint regions, 64B-line
// aligned per 16-lane group, no RFO/contention). ATOMIC=true -> legacy
// atomicAdd fallback (only if ws too small).
template <bool ATOMIC>
__global__ __launch_bounds__(1024) void gram_kernel(const float* __restrict__ x,
                                                    float* __restrict__ part,
                                                    float* __restrict__ pooled) {
    int split = blockIdx.x;
    int b     = blockIdx.y;
    const float* v = x + (size_t)b * CDIM * HW;
    int kbase0 = split * KSLAB;

    __shared__ _Float16 lds[2][CDIM * KCH];   // 2 x 16 KB

    int t    = threadIdx.x;
    int row  = t >> 2;
    int kq   = t & 3;
    int lane = t & 63;
    int wave = t >> 6;
    int wr   = wave >> 2, wc = wave & 3;
    int lhi  = lane >> 4, llo = lane & 15;

    const float4* vrow = (const float4*)(v + (size_t)row * HW);

    f32x4 acc[4][4];
    #pragma unroll
    for (int i = 0; i < 4; ++i)
        #pragma unroll
        for (int j = 0; j < 4; ++j)
            acc[i][j] = (f32x4){0.f, 0.f, 0.f, 0.f};

    float psum = 0.f;
    float4 fa0, fa1, fb0, fb1;

    {
        int kb0 = kbase0;
        fa0 = vrow[(kb0 >> 2) + kq * 2];
        fa1 = vrow[(kb0 >> 2) + kq * 2 + 1];
        int kb1 = kbase0 + KCH;
        fb0 = vrow[(kb1 >> 2) + kq * 2];
        fb1 = vrow[(kb1 >> 2) + kq * 2 + 1];
    }

    auto body = [&](float4& g0, float4& g1, _Float16* buf, int ch) {
        float vals[8] = { g0.x, g0.y, g0.z, g0.w, g1.x, g1.y, g1.z, g1.w };
        half8 h;
        #pragma unroll
        for (int j = 0; j < 8; ++j) {
            psum += vals[j];
            h[j] = (_Float16)vals[j];
        }
        *(half8*)&buf[gswz16(row, kq * 8)] = h;
        if (ch + 2 < NCH) {
            int kb = kbase0 + (ch + 2) * KCH;
            g0 = vrow[(kb >> 2) + kq * 2];
            g1 = vrow[(kb >> 2) + kq * 2 + 1];
        }
        lds_barrier();

        half8 A[4], B[4];
        #pragma unroll
        for (int rb = 0; rb < 4; ++rb)
            A[rb] = *(const half8*)&buf[gswz16(wr * 64 + rb * 16 + llo, lhi * 8)];
        #pragma unroll
        for (int cb = 0; cb < 4; ++cb)
            B[cb] = *(const half8*)&buf[gswz16(wc * 64 + cb * 16 + llo, lhi * 8)];

        __builtin_amdgcn_s_setprio(1);
        #pragma unroll
        for (int rb = 0; rb < 4; ++rb)
            #pragma unroll
            for (int cb = 0; cb < 4; ++cb)
                acc[rb][cb] = __builtin_amdgcn_mfma_f32_16x16x32_f16(A[rb], B[cb], acc[rb][cb], 0, 0, 0);
        __builtin_amdgcn_s_setprio(0);
    };

    #pragma unroll 1
    for (int it = 0; it < NCH / 2; ++it) {
        body(fa0, fa1, (_Float16*)lds[0], it * 2);
        body(fb0, fb1, (_Float16*)lds[1], it * 2 + 1);
    }

    psum += __shfl_xor(psum, 1);
    psum += __shfl_xor(psum, 2);
    if (kq == 0) atomicAdd(&pooled[b * CDIM + row], psum);

    if (ATOMIC) {
        #pragma unroll
        for (int rb = 0; rb < 4; ++rb) {
            int r0 = wr * 64 + rb * 16 + lhi * 4;
            #pragma unroll
            for (int cb = 0; cb < 4; ++cb) {
                int c0 = wc * 64 + cb * 16 + llo;
                #pragma unroll
                for (int reg = 0; reg < 4; ++reg)
                    atomicAdd(&part[((size_t)b * CDIM + r0 + reg) * CDIM + c0], acc[rb][cb][reg]);
            }
        }
    } else {
        float* pb = part + ((size_t)split * BATCH + b) * CDIM * CDIM;
        #pragma unroll
        for (int rb = 0; rb < 4; ++rb) {
            int r0 = wr * 64 + rb * 16 + lhi * 4;
            #pragma unroll
            for (int cb = 0; cb < 4; ++cb) {
                int c0 = wc * 64 + cb * 16 + llo;
                #pragma unroll
                for (int reg = 0; reg < 4; ++reg)
                    pb[(size_t)(r0 + reg) * CDIM + c0] = acc[rb][cb][reg];
            }
        }
    }
}

// ---------------- K2: SE MLP -> sigmoid gate ----------------
__global__ __launch_bounds__(256) void se_kernel(const float* __restrict__ pooled,
                                                 const float* __restrict__ w1,
                                                 const float* __restrict__ b1,
                                                 const float* __restrict__ w2,
                                                 const float* __restrict__ b2,
                                                 float* __restrict__ gate) {
    int b = blockIdx.x;
    int t = threadIdx.x;
    __shared__ float p[CDIM];
    __shared__ float hid[RDIM];
    p[t] = pooled[b * CDIM + t] * (1.0f / HW);
    __syncthreads();
    if (t < RDIM) {
        float s = b1[t];
        const float* wr = w1 + t * CDIM;
        for (int k = 0; k < CDIM; ++k) s = fmaf(wr[k], p[k], s);
        hid[t] = s > 0.f ? s : 0.f;
    }
    __syncthreads();
    float s = b2[t];
    const float* wr = w2 + t * RDIM;
    #pragma unroll
    for (int k = 0; k < RDIM; ++k) s = fmaf(wr[k], hid[k], s);
    gate[b * CDIM + t] = 1.0f / (1.0f + expf(-s));
}

// ---------------- K3: reduce NS partials + softmax -> bf16 pre-swizzled att ----
__global__ __launch_bounds__(256) void softmax_kernel(const float* __restrict__ part,
                                                      unsigned short* __restrict__ atts) {
    int row = blockIdx.x;              // b*C + c
    int b = row >> 8, c = row & 255;
    int t = threadIdx.x;               // t = d
    const float* p0 = part + (size_t)row * CDIM + t;
    float val = 0.f;
    #pragma unroll
    for (int s = 0; s < SPLITS; ++s)
        val += p0[(size_t)s * BATCH * CDIM * CDIM];

    float m = val;
    for (int off = 32; off > 0; off >>= 1) m = fminf(m, __shfl_down(m, off));
    __shared__ float redm[4];
    if ((t & 63) == 0) redm[t >> 6] = m;
    __syncthreads();
    float rowmin = fminf(fminf(redm[0], redm[1]), fminf(redm[2], redm[3]));

    float p = expf(rowmin - val);
    float s = p;
    for (int off = 32; off > 0; off >>= 1) s += __shfl_down(s, off);
    __shared__ float reds[4];
    if ((t & 63) == 0) reds[t >> 6] = s;
    __syncthreads();
    float tot = reds[0] + reds[1] + reds[2] + reds[3];

    size_t idx = (size_t)b * 65536 + (size_t)(t >> 6) * 16384 + (bofs(c, t & 63) >> 1);
    atts[idx] = bf16_rne(p / tot);
}

// single-buffer (atomic fallback) softmax: NS=1
__global__ __launch_bounds__(256) void softmax1_kernel(const float* __restrict__ energy,
                                                       unsigned short* __restrict__ atts) {
    int row = blockIdx.x;
    int b = row >> 8, c = row & 255;
    int t = threadIdx.x;
    float val = energy[(size_t)row * CDIM + t];

    float m = val;
    for (int off = 32; off > 0; off >>= 1) m = fminf(m, __shfl_down(m, off));
    __shared__ float redm[4];
    if ((t & 63) == 0) redm[t >> 6] = m;
    __syncthreads();
    float rowmin = fminf(fminf(redm[0], redm[1]), fminf(redm[2], redm[3]));

    float p = expf(rowmin - val);
    float s = p;
    for (int off = 32; off > 0; off >>= 1) s += __shfl_down(s, off);
    __shared__ float reds[4];
    if ((t & 63) == 0) reds[t >> 6] = s;
    __syncthreads();
    float tot = reds[0] + reds[1] + reds[2] + reds[3];

    size_t idx = (size_t)b * 65536 + (size_t)(t >> 6) * 16384 + (bofs(c, t & 63) >> 1);
    atts[idx] = bf16_rne(p / tot);
}

// ---------------- K4: out = gamma * gate * (att @ v) + x  (bf16 MFMA) ----------
// UNCHANGED from R11 (512 thr, 2 blocks/CU, att via global_load_lds).
__global__ __launch_bounds__(512, 4) void out_kernel(const unsigned short* __restrict__ atts,
                                                     const float* __restrict__ x,
                                                     const float* __restrict__ gate,
                                                     const float* __restrict__ gammap,
                                                     float* __restrict__ out) {
    __shared__ __align__(16) char lds[49152];   // att 32KB @0, v^T 16KB @VOFF

    const int t    = threadIdx.x;
    const int lane = t & 63;
    const int wave = t >> 6;         // 0..7
    const int wn   = wave >> 2;      // 0..1  (n)
    const int wcc  = wave & 3;       // 0..3  (c)
    const int lhi  = lane >> 4, llo = lane & 15;
    const int nblk = blockIdx.x * BN;
    const int b    = blockIdx.y;

    const float* v     = x + (size_t)b * CDIM * HW;
    const char*  attsB = (const char*)atts + (size_t)b * 131072;

    f32x4 acc[4][4];   // [rb over n][cb over c]
    #pragma unroll
    for (int i = 0; i < 4; ++i)
        #pragma unroll
        for (int j = 0; j < 4; ++j)
            acc[i][j] = (f32x4){0.f, 0.f, 0.f, 0.f};

    const int ddp = t >> 4;          // 0..31
    const int n4  = (t & 15) * 4;    // 0..60; second quad at +64
    float4 va0[2], va1[2];

    auto load_v = [&](int k0) {
        #pragma unroll
        for (int i = 0; i < 2; ++i) {
            const float* r0 = v + (size_t)(k0 + 2 * ddp) * HW + nblk + n4 + 64 * i;
            va0[i] = *(const float4*)r0;
            va1[i] = *(const float4*)(r0 + HW);
        }
    };

    load_v(0);

    for (int ch = 0; ch < 4; ++ch) {
        __syncthreads();
        #pragma unroll
        for (int i = 0; i < 4; ++i)
            gload16(attsB + ch * 32768 + i * 8192 + t * 16, lds + i * 8192 + t * 16);
        #pragma unroll
        for (int i = 0; i < 2; ++i) {
            const float* f0 = (const float*)&va0[i];
            const float* f1 = (const float*)&va1[i];
            #pragma unroll
            for (int j = 0; j < 4; ++j) {
                int n = n4 + 64 * i + j;
                *(unsigned*)(lds + VOFF + bofs(n, 2 * ddp)) = pack2(f0[j], f1[j]);
            }
        }
        __syncthreads();

        if (ch < 3) load_v((ch + 1) * BK);

        #pragma unroll
        for (int ks = 0; ks < 2; ++ks) {
            int kb = ks * 32 + lhi * 8;
            short8 An[4], Bc[4];
            #pragma unroll
            for (int rb = 0; rb < 4; ++rb)
                An[rb] = *(const short8*)(lds + VOFF + bofs(wn * 64 + rb * 16 + llo, kb));
            #pragma unroll
            for (int cb = 0; cb < 4; ++cb)
                Bc[cb] = *(const short8*)(lds + bofs(wcc * 64 + cb * 16 + llo, kb));
            #pragma unroll
            for (int rb = 0; rb < 4; ++rb)
                #pragma unroll
                for (int cb = 0; cb < 4; ++cb)
                    acc[rb][cb] = __builtin_amdgcn_mfma_f32_16x16x32_bf16(An[rb], Bc[cb], acc[rb][cb], 0, 0, 0);
        }
    }

    float gm = gammap[0];
    float gv[4];
    #pragma unroll
    for (int cb = 0; cb < 4; ++cb)
        gv[cb] = gm * gate[b * CDIM + wcc * 64 + cb * 16 + llo];

    #pragma unroll
    for (int rb = 0; rb < 4; ++rb) {
        int n0 = wn * 64 + rb * 16 + lhi * 4;
        #pragma unroll
        for (int cb = 0; cb < 4; ++cb) {
            int c = wcc * 64 + cb * 16 + llo;
            size_t base = ((size_t)b * CDIM + c) * HW + nblk + n0;
            float4 xv = *(const float4*)&x[base];
            float4 o;
            o.x = fmaf(acc[rb][cb][0], gv[cb], xv.x);
            o.y = fmaf(acc[rb][cb][1], gv[cb], xv.y);
            o.z = fmaf(acc[rb][cb][2], gv[cb], xv.z);
            o.w = fmaf(acc[rb][cb][3], gv[cb], xv.w);
            *(float4*)&out[base] = o;
        }
    }
}

extern "C" void kernel_launch(void* const* d_in, const int* in_sizes, int n_in,
                              void* d_out, int out_size, void* d_ws, size_t ws_size,
                              hipStream_t stream) {
    const float* x     = (const float*)d_in[0];
    const float* gamma = (const float*)d_in[1];
    const float* w1    = (const float*)d_in[2];
    const float* b1    = (const float*)d_in[3];
    const float* w2    = (const float*)d_in[4];
    const float* b2    = (const float*)d_in[5];
    float* out = (float*)d_out;

    const size_t ee        = (size_t)BATCH * CDIM * CDIM;   // 1 Mi elems
    const size_t partElems = (size_t)SPLITS * ee;           // 16 Mi floats = 64 MB
    const size_t needPart  = partElems * sizeof(float) + ee * 2 + 2 * BATCH * CDIM * sizeof(float);

    if (ws_size >= needPart) {
        float*          part   = (float*)d_ws;                                // 64 MB
        unsigned short* atts   = (unsigned short*)(part + partElems);         // 2 MB
        float*          pooled = (float*)(atts + ee);
        float*          gate   = pooled + BATCH * CDIM;

        hipMemsetAsync(pooled, 0, (size_t)BATCH * CDIM * sizeof(float), stream);
        gram_kernel<false><<<dim3(SPLITS, BATCH), 1024, 0, stream>>>(x, part, pooled);
        se_kernel<<<BATCH, 256, 0, stream>>>(pooled, w1, b1, w2, b2, gate);
        softmax_kernel<<<BATCH * CDIM, 256, 0, stream>>>(part, atts);
        out_kernel<<<dim3(HW / BN, BATCH), 512, 0, stream>>>(atts, x, gate, gamma, out);
    } else {
        float*          energy = (float*)d_ws;                                // 4 MB
        unsigned short* atts   = (unsigned short*)(energy + ee);              // 2 MB
        float*          pooled = (float*)(atts + ee);
        float*          gate   = pooled + BATCH * CDIM;

        hipMemsetAsync(energy, 0, ee * sizeof(float), stream);
        hipMemsetAsync(pooled, 0, (size_t)BATCH * CDIM * sizeof(float), stream);
        gram_kernel<true><<<dim3(SPLITS, BATCH), 1024, 0, stream>>>(x, energy, pooled);
        se_kernel<<<BATCH, 256, 0, stream>>>(pooled, w1, b1, w2, b2, gate);
        softmax1_kernel<<<BATCH * CDIM, 256, 0, stream>>>(energy, atts);
        out_kernel<<<dim3(HW / BN, BATCH), 512, 0, stream>>>(atts, x, gate, gamma, out);
    }
}

// Round 14
// 179.719 us; speedup vs baseline: 1.9148x; 1.0549x over previous
//
#include <hip/hip_runtime.h>
#include <math.h>

#define BATCH 16
#define CDIM 256
#define HW 9216
#define RDIM 32
#define SPLITS 16
#define KSLAB (HW / SPLITS)   /* 576 */
#define KCH 32                /* gram k-columns per chunk */
#define NCH (KSLAB / KCH)     /* 18, even */

#define BN 128                /* out_kernel n-tile */
#define BK 64                 /* out_kernel k-chunk */
#define VOFF 32768            /* v^T tile byte offset inside shared block */

typedef __attribute__((ext_vector_type(8))) short short8;
typedef __attribute__((ext_vector_type(4))) short short4_t;
typedef __attribute__((ext_vector_type(4))) float f32x4;
typedef __attribute__((ext_vector_type(8))) _Float16 half8;

__device__ __forceinline__ unsigned short bf16_rne(float x) {
    union { float f; unsigned u; } a; a.f = x;
    return (unsigned short)((a.u + 0x7fffu + ((a.u >> 16) & 1u)) >> 16);
}
__device__ __forceinline__ unsigned pack2(float lo, float hi) {
    return (unsigned)bf16_rne(lo) | ((unsigned)bf16_rne(hi) << 16);
}

// Non-draining barrier: ds ops visible, global loads STAY IN FLIGHT (gram only).
__device__ __forceinline__ void lds_barrier() {
    asm volatile("s_waitcnt lgkmcnt(0)" ::: "memory");
    __builtin_amdgcn_s_barrier();
}

// async 16B global->LDS copy
__device__ __forceinline__ void gload16(const void* g, void* l) {
    __builtin_amdgcn_global_load_lds(
        (const __attribute__((address_space(1))) unsigned*)g,
        (__attribute__((address_space(3))) unsigned*)l, 16, 0, 0);
}

// gram fp16 tile [256 rows][32 k], row stride 64 B (2-way max conflicts).
__device__ __forceinline__ int gswz16(int row, int k) {
    int byte = (row << 6) + (k << 1);
    byte ^= (((row >> 1) ^ (row >> 3)) & 3) << 4;
    return byte >> 1;
}
// out-kernel swizzle (row stride 128 B); byte offset in a [*][64] bf16 tile.
__device__ __forceinline__ int bofs(int row, int k) {
    return (((row) << 7) | ((k) << 1)) ^ (((row ^ (row >> 2)) & 7) << 4);
}

// ---------------- K1: energy partials = v v^T (split-K, fp16 MFMA) ----------
// R6-proven pipeline. Partial epilogue: NONTEMPORAL fp32 stores (streaming
// data, single consumer -> keep out of L2/L3). Atomic fallback unchanged.
template <bool ATOMIC>
__global__ __launch_bounds__(1024) void gram_kernel(const float* __restrict__ x,
                                                    float* __restrict__ part,
                                                    float* __restrict__ pooled) {
    int split = blockIdx.x;
    int b     = blockIdx.y;
    const float* v = x + (size_t)b * CDIM * HW;
    int kbase0 = split * KSLAB;

    __shared__ _Float16 lds[2][CDIM * KCH];   // 2 x 16 KB

    int t    = threadIdx.x;
    int row  = t >> 2;
    int kq   = t & 3;
    int lane = t & 63;
    int wave = t >> 6;
    int wr   = wave >> 2, wc = wave & 3;
    int lhi  = lane >> 4, llo = lane & 15;

    const float4* vrow = (const float4*)(v + (size_t)row * HW);

    f32x4 acc[4][4];
    #pragma unroll
    for (int i = 0; i < 4; ++i)
        #pragma unroll
        for (int j = 0; j < 4; ++j)
            acc[i][j] = (f32x4){0.f, 0.f, 0.f, 0.f};

    float psum = 0.f;
    float4 fa0, fa1, fb0, fb1;

    {
        int kb0 = kbase0;
        fa0 = vrow[(kb0 >> 2) + kq * 2];
        fa1 = vrow[(kb0 >> 2) + kq * 2 + 1];
        int kb1 = kbase0 + KCH;
        fb0 = vrow[(kb1 >> 2) + kq * 2];
        fb1 = vrow[(kb1 >> 2) + kq * 2 + 1];
    }

    auto body = [&](float4& g0, float4& g1, _Float16* buf, int ch) {
        float vals[8] = { g0.x, g0.y, g0.z, g0.w, g1.x, g1.y, g1.z, g1.w };
        half8 h;
        #pragma unroll
        for (int j = 0; j < 8; ++j) {
            psum += vals[j];
            h[j] = (_Float16)vals[j];
        }
        *(half8*)&buf[gswz16(row, kq * 8)] = h;
        if (ch + 2 < NCH) {
            int kb = kbase0 + (ch + 2) * KCH;
            g0 = vrow[(kb >> 2) + kq * 2];
            g1 = vrow[(kb >> 2) + kq * 2 + 1];
        }
        lds_barrier();

        half8 A[4], B[4];
        #pragma unroll
        for (int rb = 0; rb < 4; ++rb)
            A[rb] = *(const half8*)&buf[gswz16(wr * 64 + rb * 16 + llo, lhi * 8)];
        #pragma unroll
        for (int cb = 0; cb < 4; ++cb)
            B[cb] = *(const half8*)&buf[gswz16(wc * 64 + cb * 16 + llo, lhi * 8)];

        __builtin_amdgcn_s_setprio(1);
        #pragma unroll
        for (int rb = 0; rb < 4; ++rb)
            #pragma unroll
            for (int cb = 0; cb < 4; ++cb)
                acc[rb][cb] = __builtin_amdgcn_mfma_f32_16x16x32_f16(A[rb], B[cb], acc[rb][cb], 0, 0, 0);
        __builtin_amdgcn_s_setprio(0);
    };

    #pragma unroll 1
    for (int it = 0; it < NCH / 2; ++it) {
        body(fa0, fa1, (_Float16*)lds[0], it * 2);
        body(fb0, fb1, (_Float16*)lds[1], it * 2 + 1);
    }

    psum += __shfl_xor(psum, 1);
    psum += __shfl_xor(psum, 2);
    if (kq == 0) atomicAdd(&pooled[b * CDIM + row], psum);

    if (ATOMIC) {
        #pragma unroll
        for (int rb = 0; rb < 4; ++rb) {
            int r0 = wr * 64 + rb * 16 + lhi * 4;
            #pragma unroll
            for (int cb = 0; cb < 4; ++cb) {
                int c0 = wc * 64 + cb * 16 + llo;
                #pragma unroll
                for (int reg = 0; reg < 4; ++reg)
                    atomicAdd(&part[((size_t)b * CDIM + r0 + reg) * CDIM + c0], acc[rb][cb][reg]);
            }
        }
    } else {
        float* pb = part + ((size_t)split * BATCH + b) * CDIM * CDIM;
        #pragma unroll
        for (int rb = 0; rb < 4; ++rb) {
            int r0 = wr * 64 + rb * 16 + lhi * 4;
            #pragma unroll
            for (int cb = 0; cb < 4; ++cb) {
                int c0 = wc * 64 + cb * 16 + llo;
                #pragma unroll
                for (int reg = 0; reg < 4; ++reg)
                    __builtin_nontemporal_store(acc[rb][cb][reg],
                        &pb[(size_t)(r0 + reg) * CDIM + c0]);
            }
        }
    }
}

// ---------------- K2: SE MLP -> sigmoid gate ----------------
__global__ __launch_bounds__(256) void se_kernel(const float* __restrict__ pooled,
                                                 const float* __restrict__ w1,
                                                 const float* __restrict__ b1,
                                                 const float* __restrict__ w2,
                                                 const float* __restrict__ b2,
                                                 float* __restrict__ gate) {
    int b = blockIdx.x;
    int t = threadIdx.x;
    __shared__ float p[CDIM];
    __shared__ float hid[RDIM];
    p[t] = pooled[b * CDIM + t] * (1.0f / HW);
    __syncthreads();
    if (t < RDIM) {
        float s = b1[t];
        const float* wr = w1 + t * CDIM;
        for (int k = 0; k < CDIM; ++k) s = fmaf(wr[k], p[k], s);
        hid[t] = s > 0.f ? s : 0.f;
    }
    __syncthreads();
    float s = b2[t];
    const float* wr = w2 + t * RDIM;
    #pragma unroll
    for (int k = 0; k < RDIM; ++k) s = fmaf(wr[k], hid[k], s);
    gate[b * CDIM + t] = 1.0f / (1.0f + expf(-s));
}

// ---------------- K3: reduce partials (NT loads) + softmax -> bf16 att image ----
__global__ __launch_bounds__(256) void softmax_kernel(const float* __restrict__ part,
                                                      unsigned short* __restrict__ atts) {
    int row = blockIdx.x;              // b*C + c
    int b = row >> 8, c = row & 255;
    int t = threadIdx.x;               // t = d
    const float* p0 = part + (size_t)row * CDIM + t;
    float val = 0.f;
    #pragma unroll
    for (int s = 0; s < SPLITS; ++s)
        val += __builtin_nontemporal_load(&p0[(size_t)s * BATCH * CDIM * CDIM]);

    float m = val;
    for (int off = 32; off > 0; off >>= 1) m = fminf(m, __shfl_down(m, off));
    __shared__ float redm[4];
    if ((t & 63) == 0) redm[t >> 6] = m;
    __syncthreads();
    float rowmin = fminf(fminf(redm[0], redm[1]), fminf(redm[2], redm[3]));

    float p = expf(rowmin - val);
    float s = p;
    for (int off = 32; off > 0; off >>= 1) s += __shfl_down(s, off);
    __shared__ float reds[4];
    if ((t & 63) == 0) reds[t >> 6] = s;
    __syncthreads();
    float tot = reds[0] + reds[1] + reds[2] + reds[3];

    size_t idx = (size_t)b * 65536 + (size_t)(t >> 6) * 16384 + (bofs(c, t & 63) >> 1);
    atts[idx] = bf16_rne(p / tot);   // normal store: re-read 72x by out_kernel
}

// single-buffer (atomic fallback) softmax: NS=1
__global__ __launch_bounds__(256) void softmax1_kernel(const float* __restrict__ energy,
                                                       unsigned short* __restrict__ atts) {
    int row = blockIdx.x;
    int b = row >> 8, c = row & 255;
    int t = threadIdx.x;
    float val = energy[(size_t)row * CDIM + t];

    float m = val;
    for (int off = 32; off > 0; off >>= 1) m = fminf(m, __shfl_down(m, off));
    __shared__ float redm[4];
    if ((t & 63) == 0) redm[t >> 6] = m;
    __syncthreads();
    float rowmin = fminf(fminf(redm[0], redm[1]), fminf(redm[2], redm[3]));

    float p = expf(rowmin - val);
    float s = p;
    for (int off = 32; off > 0; off >>= 1) s += __shfl_down(s, off);
    __shared__ float reds[4];
    if ((t & 63) == 0) reds[t >> 6] = s;
    __syncthreads();
    float tot = reds[0] + reds[1] + reds[2] + reds[3];

    size_t idx = (size_t)b * 65536 + (size_t)(t >> 6) * 16384 + (bofs(c, t & 63) >> 1);
    atts[idx] = bf16_rne(p / tot);
}

// ---------------- K4: out = gamma * gate * (att @ v) + x  (bf16 MFMA) ----------
// R11/R12 structure; epilogue stores NONTEMPORAL (write-once stream).
__global__ __launch_bounds__(512, 4) void out_kernel(const unsigned short* __restrict__ atts,
                                                     const float* __restrict__ x,
                                                     const float* __restrict__ gate,
                                                     const float* __restrict__ gammap,
                                                     float* __restrict__ out) {
    __shared__ __align__(16) char lds[49152];   // att 32KB @0, v^T 16KB @VOFF

    const int t    = threadIdx.x;
    const int lane = t & 63;
    const int wave = t >> 6;         // 0..7
    const int wn   = wave >> 2;      // 0..1  (n)
    const int wcc  = wave & 3;       // 0..3  (c)
    const int lhi  = lane >> 4, llo = lane & 15;
    const int nblk = blockIdx.x * BN;
    const int b    = blockIdx.y;

    const float* v     = x + (size_t)b * CDIM * HW;
    const char*  attsB = (const char*)atts + (size_t)b * 131072;

    f32x4 acc[4][4];   // [rb over n][cb over c]
    #pragma unroll
    for (int i = 0; i < 4; ++i)
        #pragma unroll
        for (int j = 0; j < 4; ++j)
            acc[i][j] = (f32x4){0.f, 0.f, 0.f, 0.f};

    const int ddp = t >> 4;          // 0..31
    const int n4  = (t & 15) * 4;    // 0..60; second quad at +64
    float4 va0[2], va1[2];

    auto load_v = [&](int k0) {
        #pragma unroll
        for (int i = 0; i < 2; ++i) {
            const float* r0 = v + (size_t)(k0 + 2 * ddp) * HW + nblk + n4 + 64 * i;
            va0[i] = *(const float4*)r0;
            va1[i] = *(const float4*)(r0 + HW);
        }
    };

    load_v(0);

    for (int ch = 0; ch < 4; ++ch) {
        __syncthreads();
        #pragma unroll
        for (int i = 0; i < 4; ++i)
            gload16(attsB + ch * 32768 + i * 8192 + t * 16, lds + i * 8192 + t * 16);
        #pragma unroll
        for (int i = 0; i < 2; ++i) {
            const float* f0 = (const float*)&va0[i];
            const float* f1 = (const float*)&va1[i];
            #pragma unroll
            for (int j = 0; j < 4; ++j) {
                int n = n4 + 64 * i + j;
                *(unsigned*)(lds + VOFF + bofs(n, 2 * ddp)) = pack2(f0[j], f1[j]);
            }
        }
        __syncthreads();

        if (ch < 3) load_v((ch + 1) * BK);

        #pragma unroll
        for (int ks = 0; ks < 2; ++ks) {
            int kb = ks * 32 + lhi * 8;
            short8 An[4], Bc[4];
            #pragma unroll
            for (int rb = 0; rb < 4; ++rb)
                An[rb] = *(const short8*)(lds + VOFF + bofs(wn * 64 + rb * 16 + llo, kb));
            #pragma unroll
            for (int cb = 0; cb < 4; ++cb)
                Bc[cb] = *(const short8*)(lds + bofs(wcc * 64 + cb * 16 + llo, kb));
            #pragma unroll
            for (int rb = 0; rb < 4; ++rb)
                #pragma unroll
                for (int cb = 0; cb < 4; ++cb)
                    acc[rb][cb] = __builtin_amdgcn_mfma_f32_16x16x32_bf16(An[rb], Bc[cb], acc[rb][cb], 0, 0, 0);
        }
    }

    float gm = gammap[0];
    float gv[4];
    #pragma unroll
    for (int cb = 0; cb < 4; ++cb)
        gv[cb] = gm * gate[b * CDIM + wcc * 64 + cb * 16 + llo];

    #pragma unroll
    for (int rb = 0; rb < 4; ++rb) {
        int n0 = wn * 64 + rb * 16 + lhi * 4;
        #pragma unroll
        for (int cb = 0; cb < 4; ++cb) {
            int c = wcc * 64 + cb * 16 + llo;
            size_t base = ((size_t)b * CDIM + c) * HW + nblk + n0;
            f32x4 xv = *(const f32x4*)&x[base];
            f32x4 o;
            o[0] = fmaf(acc[rb][cb][0], gv[cb], xv[0]);
            o[1] = fmaf(acc[rb][cb][1], gv[cb], xv[1]);
            o[2] = fmaf(acc[rb][cb][2], gv[cb], xv[2]);
            o[3] = fmaf(acc[rb][cb][3], gv[cb], xv[3]);
            __builtin_nontemporal_store(o, (f32x4*)&out[base]);
        }
    }
}

extern "C" void kernel_launch(void* const* d_in, const int* in_sizes, int n_in,
                              void* d_out, int out_size, void* d_ws, size_t ws_size,
                              hipStream_t stream) {
    const float* x     = (const float*)d_in[0];
    const float* gamma = (const float*)d_in[1];
    const float* w1    = (const float*)d_in[2];
    const float* b1    = (const float*)d_in[3];
    const float* w2    = (const float*)d_in[4];
    const float* b2    = (const float*)d_in[5];
    float* out = (float*)d_out;

    const size_t ee        = (size_t)BATCH * CDIM * CDIM;   // 1 Mi elems
    const size_t partElems = (size_t)SPLITS * ee;           // 16 Mi floats = 64 MB
    const size_t needPart  = partElems * sizeof(float) + ee * 2 + 2 * BATCH * CDIM * sizeof(float);

    if (ws_size >= needPart) {
        float*          part   = (float*)d_ws;                                // 64 MB
        unsigned short* atts   = (unsigned short*)(part + partElems);         // 2 MB
        float*          pooled = (float*)(atts + ee);
        float*          gate   = pooled + BATCH * CDIM;

        hipMemsetAsync(pooled, 0, (size_t)BATCH * CDIM * sizeof(float), stream);
        gram_kernel<false><<<dim3(SPLITS, BATCH), 1024, 0, stream>>>(x, part, pooled);
        se_kernel<<<BATCH, 256, 0, stream>>>(pooled, w1, b1, w2, b2, gate);
        softmax_kernel<<<BATCH * CDIM, 256, 0, stream>>>(part, atts);
        out_kernel<<<dim3(HW / BN, BATCH), 512, 0, stream>>>(atts, x, gate, gamma, out);
    } else {
        float*          energy = (float*)d_ws;                                // 4 MB
        unsigned short* atts   = (unsigned short*)(energy + ee);              // 2 MB
        float*          pooled = (float*)(atts + ee);
        float*          gate   = pooled + BATCH * CDIM;

        hipMemsetAsync(energy, 0, ee * sizeof(float), stream);
        hipMemsetAsync(pooled, 0, (size_t)BATCH * CDIM * sizeof(float), stream);
        gram_kernel<true><<<dim3(SPLITS, BATCH), 1024, 0, stream>>>(x, energy, pooled);
        se_kernel<<<BATCH, 256, 0, stream>>>(pooled, w1, b1, w2, b2, gate);
        softmax1_kernel<<<BATCH * CDIM, 256, 0, stream>>>(energy, atts);
        out_kernel<<<dim3(HW / BN, BATCH), 512, 0, stream>>>(atts, x, gate, gamma, out);
    }
}

// Round 15
// 170.221 us; speedup vs baseline: 2.0217x; 1.0558x over previous
//
#include <hip/hip_runtime.h>
#include <math.h>

#define BATCH 16
#define CDIM 256
#define HW 9216
#define RDIM 32
#define SPLITS 16
#define KSLAB (HW / SPLITS)   /* 576 */
#define KCH 32                /* gram k-columns per chunk */
#define NCH (KSLAB / KCH)     /* 18, even */

#define BN 64                 /* out_kernel n-tile */
#define BK 64                 /* out_kernel k-chunk */
#define VOFF 32768            /* v^T tile byte offset inside shared block */

typedef __attribute__((ext_vector_type(8))) short short8;
typedef __attribute__((ext_vector_type(4))) short short4_t;
typedef __attribute__((ext_vector_type(4))) float f32x4;
typedef __attribute__((ext_vector_type(8))) _Float16 half8;

__device__ __forceinline__ unsigned short bf16_rne(float x) {
    union { float f; unsigned u; } a; a.f = x;
    return (unsigned short)((a.u + 0x7fffu + ((a.u >> 16) & 1u)) >> 16);
}
__device__ __forceinline__ unsigned pack2(float lo, float hi) {
    return (unsigned)bf16_rne(lo) | ((unsigned)bf16_rne(hi) << 16);
}

// Non-draining barrier: ds ops visible, global loads STAY IN FLIGHT (gram only).
__device__ __forceinline__ void lds_barrier() {
    asm volatile("s_waitcnt lgkmcnt(0)" ::: "memory");
    __builtin_amdgcn_s_barrier();
}

// async 16B global->LDS copy
__device__ __forceinline__ void gload16(const void* g, void* l) {
    __builtin_amdgcn_global_load_lds(
        (const __attribute__((address_space(1))) unsigned*)g,
        (__attribute__((address_space(3))) unsigned*)l, 16, 0, 0);
}

// gram fp16 tile [256 rows][32 k], row stride 64 B (2-way max conflicts).
__device__ __forceinline__ int gswz16(int row, int k) {
    int byte = (row << 6) + (k << 1);
    byte ^= (((row >> 1) ^ (row >> 3)) & 3) << 4;
    return byte >> 1;
}
// out-kernel swizzle (row stride 128 B); byte offset in a [*][64] bf16 tile.
__device__ __forceinline__ int bofs(int row, int k) {
    return (((row) << 7) | ((k) << 1)) ^ (((row ^ (row >> 2)) & 7) << 4);
}

// ---------------- K1: energy partials = v v^T (split-K, fp16 MFMA) ----------
// UNCHANGED from R14 (proven): NT partial stores; atomic fallback.
template <bool ATOMIC>
__global__ __launch_bounds__(1024) void gram_kernel(const float* __restrict__ x,
                                                    float* __restrict__ part,
                                                    float* __restrict__ pooled) {
    int split = blockIdx.x;
    int b     = blockIdx.y;
    const float* v = x + (size_t)b * CDIM * HW;
    int kbase0 = split * KSLAB;

    __shared__ _Float16 lds[2][CDIM * KCH];   // 2 x 16 KB

    int t    = threadIdx.x;
    int row  = t >> 2;
    int kq   = t & 3;
    int lane = t & 63;
    int wave = t >> 6;
    int wr   = wave >> 2, wc = wave & 3;
    int lhi  = lane >> 4, llo = lane & 15;

    const float4* vrow = (const float4*)(v + (size_t)row * HW);

    f32x4 acc[4][4];
    #pragma unroll
    for (int i = 0; i < 4; ++i)
        #pragma unroll
        for (int j = 0; j < 4; ++j)
            acc[i][j] = (f32x4){0.f, 0.f, 0.f, 0.f};

    float psum = 0.f;
    float4 fa0, fa1, fb0, fb1;

    {
        int kb0 = kbase0;
        fa0 = vrow[(kb0 >> 2) + kq * 2];
        fa1 = vrow[(kb0 >> 2) + kq * 2 + 1];
        int kb1 = kbase0 + KCH;
        fb0 = vrow[(kb1 >> 2) + kq * 2];
        fb1 = vrow[(kb1 >> 2) + kq * 2 + 1];
    }

    auto body = [&](float4& g0, float4& g1, _Float16* buf, int ch) {
        float vals[8] = { g0.x, g0.y, g0.z, g0.w, g1.x, g1.y, g1.z, g1.w };
        half8 h;
        #pragma unroll
        for (int j = 0; j < 8; ++j) {
            psum += vals[j];
            h[j] = (_Float16)vals[j];
        }
        *(half8*)&buf[gswz16(row, kq * 8)] = h;
        if (ch + 2 < NCH) {
            int kb = kbase0 + (ch + 2) * KCH;
            g0 = vrow[(kb >> 2) + kq * 2];
            g1 = vrow[(kb >> 2) + kq * 2 + 1];
        }
        lds_barrier();

        half8 A[4], B[4];
        #pragma unroll
        for (int rb = 0; rb < 4; ++rb)
            A[rb] = *(const half8*)&buf[gswz16(wr * 64 + rb * 16 + llo, lhi * 8)];
        #pragma unroll
        for (int cb = 0; cb < 4; ++cb)
            B[cb] = *(const half8*)&buf[gswz16(wc * 64 + cb * 16 + llo, lhi * 8)];

        __builtin_amdgcn_s_setprio(1);
        #pragma unroll
        for (int rb = 0; rb < 4; ++rb)
            #pragma unroll
            for (int cb = 0; cb < 4; ++cb)
                acc[rb][cb] = __builtin_amdgcn_mfma_f32_16x16x32_f16(A[rb], B[cb], acc[rb][cb], 0, 0, 0);
        __builtin_amdgcn_s_setprio(0);
    };

    #pragma unroll 1
    for (int it = 0; it < NCH / 2; ++it) {
        body(fa0, fa1, (_Float16*)lds[0], it * 2);
        body(fb0, fb1, (_Float16*)lds[1], it * 2 + 1);
    }

    psum += __shfl_xor(psum, 1);
    psum += __shfl_xor(psum, 2);
    if (kq == 0) atomicAdd(&pooled[b * CDIM + row], psum);

    if (ATOMIC) {
        #pragma unroll
        for (int rb = 0; rb < 4; ++rb) {
            int r0 = wr * 64 + rb * 16 + lhi * 4;
            #pragma unroll
            for (int cb = 0; cb < 4; ++cb) {
                int c0 = wc * 64 + cb * 16 + llo;
                #pragma unroll
                for (int reg = 0; reg < 4; ++reg)
                    atomicAdd(&part[((size_t)b * CDIM + r0 + reg) * CDIM + c0], acc[rb][cb][reg]);
            }
        }
    } else {
        float* pb = part + ((size_t)split * BATCH + b) * CDIM * CDIM;
        #pragma unroll
        for (int rb = 0; rb < 4; ++rb) {
            int r0 = wr * 64 + rb * 16 + lhi * 4;
            #pragma unroll
            for (int cb = 0; cb < 4; ++cb) {
                int c0 = wc * 64 + cb * 16 + llo;
                #pragma unroll
                for (int reg = 0; reg < 4; ++reg)
                    __builtin_nontemporal_store(acc[rb][cb][reg],
                        &pb[(size_t)(r0 + reg) * CDIM + c0]);
            }
        }
    }
}

// ---------------- K2: SE MLP -> sigmoid gate ----------------
__global__ __launch_bounds__(256) void se_kernel(const float* __restrict__ pooled,
                                                 const float* __restrict__ w1,
                                                 const float* __restrict__ b1,
                                                 const float* __restrict__ w2,
                                                 const float* __restrict__ b2,
                                                 float* __restrict__ gate) {
    int b = blockIdx.x;
    int t = threadIdx.x;
    __shared__ float p[CDIM];
    __shared__ float hid[RDIM];
    p[t] = pooled[b * CDIM + t] * (1.0f / HW);
    __syncthreads();
    if (t < RDIM) {
        float s = b1[t];
        const float* wr = w1 + t * CDIM;
        for (int k = 0; k < CDIM; ++k) s = fmaf(wr[k], p[k], s);
        hid[t] = s > 0.f ? s : 0.f;
    }
    __syncthreads();
    float s = b2[t];
    const float* wr = w2 + t * RDIM;
    #pragma unroll
    for (int k = 0; k < RDIM; ++k) s = fmaf(wr[k], hid[k], s);
    gate[b * CDIM + t] = 1.0f / (1.0f + expf(-s));
}

// ---------------- K3: reduce partials (NT loads) + softmax -> bf16 att image ----
__global__ __launch_bounds__(256) void softmax_kernel(const float* __restrict__ part,
                                                      unsigned short* __restrict__ atts) {
    int row = blockIdx.x;              // b*C + c
    int b = row >> 8, c = row & 255;
    int t = threadIdx.x;               // t = d
    const float* p0 = part + (size_t)row * CDIM + t;
    float val = 0.f;
    #pragma unroll
    for (int s = 0; s < SPLITS; ++s)
        val += __builtin_nontemporal_load(&p0[(size_t)s * BATCH * CDIM * CDIM]);

    float m = val;
    for (int off = 32; off > 0; off >>= 1) m = fminf(m, __shfl_down(m, off));
    __shared__ float redm[4];
    if ((t & 63) == 0) redm[t >> 6] = m;
    __syncthreads();
    float rowmin = fminf(fminf(redm[0], redm[1]), fminf(redm[2], redm[3]));

    float p = expf(rowmin - val);
    float s = p;
    for (int off = 32; off > 0; off >>= 1) s += __shfl_down(s, off);
    __shared__ float reds[4];
    if ((t & 63) == 0) reds[t >> 6] = s;
    __syncthreads();
    float tot = reds[0] + reds[1] + reds[2] + reds[3];

    size_t idx = (size_t)b * 65536 + (size_t)(t >> 6) * 16384 + (bofs(c, t & 63) >> 1);
    atts[idx] = bf16_rne(p / tot);   // normal store: re-read by out_kernel
}

// single-buffer (atomic fallback) softmax: NS=1
__global__ __launch_bounds__(256) void softmax1_kernel(const float* __restrict__ energy,
                                                       unsigned short* __restrict__ atts) {
    int row = blockIdx.x;
    int b = row >> 8, c = row & 255;
    int t = threadIdx.x;
    float val = energy[(size_t)row * CDIM + t];

    float m = val;
    for (int off = 32; off > 0; off >>= 1) m = fminf(m, __shfl_down(m, off));
    __shared__ float redm[4];
    if ((t & 63) == 0) redm[t >> 6] = m;
    __syncthreads();
    float rowmin = fminf(fminf(redm[0], redm[1]), fminf(redm[2], redm[3]));

    float p = expf(rowmin - val);
    float s = p;
    for (int off = 32; off > 0; off >>= 1) s += __shfl_down(s, off);
    __shared__ float reds[4];
    if ((t & 63) == 0) reds[t >> 6] = s;
    __syncthreads();
    float tot = reds[0] + reds[1] + reds[2] + reds[3];

    size_t idx = (size_t)b * 65536 + (size_t)(t >> 6) * 16384 + (bofs(c, t & 63) >> 1);
    atts[idx] = bf16_rne(p / tot);
}

// ---------------- K4: out = gamma * gate * (att @ v) + x  (bf16 MFMA) ----------
// v5: 256 thr (4 waves = 4 c-groups), tile 64n x 256c, 40 KB LDS
// -> 4 blocks/CU (4 independent barrier groups per CU; each SIMD hosts 4
// waves from 4 DIFFERENT blocks -> no lockstep, latency fully covered).
// v slab read once per block (no duplication); att L2-resident.
__global__ __launch_bounds__(256, 4) void out_kernel(const unsigned short* __restrict__ atts,
                                                     const float* __restrict__ x,
                                                     const float* __restrict__ gate,
                                                     const float* __restrict__ gammap,
                                                     float* __restrict__ out) {
    __shared__ __align__(16) char lds[40960];   // att 32KB @0, v^T 8KB @VOFF

    const int t    = threadIdx.x;
    const int lane = t & 63;
    const int wave = t >> 6;         // 0..3 = c-group
    const int lhi  = lane >> 4, llo = lane & 15;
    const int nblk = blockIdx.x * BN;
    const int b    = blockIdx.y;

    const float* v     = x + (size_t)b * CDIM * HW;
    const char*  attsB = (const char*)atts + (size_t)b * 131072;

    f32x4 acc[4][4];   // [rb over n][cb over c]
    #pragma unroll
    for (int i = 0; i < 4; ++i)
        #pragma unroll
        for (int j = 0; j < 4; ++j)
            acc[i][j] = (f32x4){0.f, 0.f, 0.f, 0.f};

    // v^T staging: thread owns dd-pair (2*ddp, 2*ddp+1) x 8 consecutive n.
    const int ddp = t >> 3;          // 0..31
    const int n8  = (t & 7) * 8;     // 0..56
    float4 vr0a, vr0b, vr1a, vr1b;   // row dd: [n8..n8+3],[n8+4..n8+7]; row dd+1 same

    auto load_v = [&](int k0) {
        const float* r0 = v + (size_t)(k0 + 2 * ddp) * HW + nblk + n8;
        vr0a = *(const float4*)r0;
        vr0b = *(const float4*)(r0 + 4);
        vr1a = *(const float4*)(r0 + HW);
        vr1b = *(const float4*)(r0 + HW + 4);
    };

    load_v(0);

    for (int ch = 0; ch < 4; ++ch) {
        __syncthreads();   // prior chunk's frag reads done
        // ---- att chunk: 32KB async memcpy -> LDS (8 x 16B per thread) ----
        #pragma unroll
        for (int i = 0; i < 8; ++i)
            gload16(attsB + ch * 32768 + i * 4096 + t * 16, lds + i * 4096 + t * 16);
        // ---- v^T transpose-writes (pack2 -> u32), 8 per thread ----
        {
            const float* f0a = (const float*)&vr0a;
            const float* f0b = (const float*)&vr0b;
            const float* f1a = (const float*)&vr1a;
            const float* f1b = (const float*)&vr1b;
            #pragma unroll
            for (int j = 0; j < 4; ++j) {
                *(unsigned*)(lds + VOFF + bofs(n8 + j,     2 * ddp)) = pack2(f0a[j], f1a[j]);
                *(unsigned*)(lds + VOFF + bofs(n8 + 4 + j, 2 * ddp)) = pack2(f0b[j], f1b[j]);
            }
        }
        __syncthreads();   // tile staged (att gloads + v ds_writes drained)

        if (ch < 3) load_v((ch + 1) * BK);   // prefetch v under MFMA

        #pragma unroll
        for (int ks = 0; ks < 2; ++ks) {
            int kb = ks * 32 + lhi * 8;
            short8 An[4], Bc[4];
            #pragma unroll
            for (int rb = 0; rb < 4; ++rb)   // A = v^T rows (n, 0..63)
                An[rb] = *(const short8*)(lds + VOFF + bofs(rb * 16 + llo, kb));
            #pragma unroll
            for (int cb = 0; cb < 4; ++cb)   // B = att rows (c, wave's 64)
                Bc[cb] = *(const short8*)(lds + bofs(wave * 64 + cb * 16 + llo, kb));
            #pragma unroll
            for (int rb = 0; rb < 4; ++rb)
                #pragma unroll
                for (int cb = 0; cb < 4; ++cb)
                    acc[rb][cb] = __builtin_amdgcn_mfma_f32_16x16x32_bf16(An[rb], Bc[cb], acc[rb][cb], 0, 0, 0);
        }
    }

    // ---- epilogue: lane owns col c, 4 consecutive n -> float4 NT store ----
    float gm = gammap[0];
    float gv[4];
    #pragma unroll
    for (int cb = 0; cb < 4; ++cb)
        gv[cb] = gm * gate[b * CDIM + wave * 64 + cb * 16 + llo];

    #pragma unroll
    for (int rb = 0; rb < 4; ++rb) {
        int n0 = rb * 16 + lhi * 4;
        #pragma unroll
        for (int cb = 0; cb < 4; ++cb) {
            int c = wave * 64 + cb * 16 + llo;
            size_t base = ((size_t)b * CDIM + c) * HW + nblk + n0;
            f32x4 xv = *(const f32x4*)&x[base];
            f32x4 o;
            o[0] = fmaf(acc[rb][cb][0], gv[cb], xv[0]);
            o[1] = fmaf(acc[rb][cb][1], gv[cb], xv[1]);
            o[2] = fmaf(acc[rb][cb][2], gv[cb], xv[2]);
            o[3] = fmaf(acc[rb][cb][3], gv[cb], xv[3]);
            __builtin_nontemporal_store(o, (f32x4*)&out[base]);
        }
    }
}

extern "C" void kernel_launch(void* const* d_in, const int* in_sizes, int n_in,
                              void* d_out, int out_size, void* d_ws, size_t ws_size,
                              hipStream_t stream) {
    const float* x     = (const float*)d_in[0];
    const float* gamma = (const float*)d_in[1];
    const float* w1    = (const float*)d_in[2];
    const float* b1    = (const float*)d_in[3];
    const float* w2    = (const float*)d_in[4];
    const float* b2    = (const float*)d_in[5];
    float* out = (float*)d_out;

    const size_t ee        = (size_t)BATCH * CDIM * CDIM;   // 1 Mi elems
    const size_t partElems = (size_t)SPLITS * ee;           // 16 Mi floats = 64 MB
    const size_t needPart  = partElems * sizeof(float) + ee * 2 + 2 * BATCH * CDIM * sizeof(float);

    if (ws_size >= needPart) {
        float*          part   = (float*)d_ws;                                // 64 MB
        unsigned short* atts   = (unsigned short*)(part + partElems);         // 2 MB
        float*          pooled = (float*)(atts + ee);
        float*          gate   = pooled + BATCH * CDIM;

        hipMemsetAsync(pooled, 0, (size_t)BATCH * CDIM * sizeof(float), stream);
        gram_kernel<false><<<dim3(SPLITS, BATCH), 1024, 0, stream>>>(x, part, pooled);
        se_kernel<<<BATCH, 256, 0, stream>>>(pooled, w1, b1, w2, b2, gate);
        softmax_kernel<<<BATCH * CDIM, 256, 0, stream>>>(part, atts);
        out_kernel<<<dim3(HW / BN, BATCH), 256, 0, stream>>>(atts, x, gate, gamma, out);
    } else {
        float*          energy = (float*)d_ws;                                // 4 MB
        unsigned short* atts   = (unsigned short*)(energy + ee);              // 2 MB
        float*          pooled = (float*)(atts + ee);
        float*          gate   = pooled + BATCH * CDIM;

        hipMemsetAsync(energy, 0, ee * sizeof(float), stream);
        hipMemsetAsync(pooled, 0, (size_t)BATCH * CDIM * sizeof(float), stream);
        gram_kernel<true><<<dim3(SPLITS, BATCH), 1024, 0, stream>>>(x, energy, pooled);
        se_kernel<<<BATCH, 256, 0, stream>>>(pooled, w1, b1, w2, b2, gate);
        softmax1_kernel<<<BATCH * CDIM, 256, 0, stream>>>(energy, atts);
        out_kernel<<<dim3(HW / BN, BATCH), 256, 0, stream>>>(atts, x, gate, gamma, out);
    }
}